// Round 9
// baseline (403.595 us; speedup 1.0000x reference)
//
#include <hip/hip_runtime.h>
#include <hip/hip_bf16.h>
#include <math.h>

#define N_NODES 60000
#define E_EDGES 200000
#define DIM     128
#define NINPK   256
#define TSTEPS  6
#define LLAYERS 2
#define BGRAPH  16
#define NBINS   (TSTEPS * N_NODES)          // 360000
#define NB      ((NBINS + 1023) / 1024)     // 352 scan blocks
#define NWORDS  15000

#define B_INITP  ((NBINS + 255) / 256)          // 1407
#define B_PREP   16
#define B_HIST   ((E_EDGES + 255) / 256)        // 782
#define B_TGEMM  ((NWORDS + 127) / 128)         // 118
#define B_PLACE  ((E_EDGES + 255) / 256)        // 782
#define B_EMBED  512
#define B_LSTM   128
#define GB       ((N_NODES + 127) / 128)        // 469 (dyn early-exit on nseg)
#define B_ZZ     64
#define B_SEGMAX ((N_NODES + 63) / 64)          // 938

typedef float f32x4 __attribute__((ext_vector_type(4)));
typedef short s16x8 __attribute__((ext_vector_type(8)));
typedef short s16x4 __attribute__((ext_vector_type(4)));

static __device__ __forceinline__ float sigm(float x) { return 1.f / (1.f + expf(-x)); }

static __device__ __forceinline__ short f2bf(float f) {
  unsigned u = __float_as_uint(f);
  u += 0x7FFFu + ((u >> 16) & 1u);
  return (short)(u >> 16);
}
static __device__ __forceinline__ float bf2f(short s) {
  return __uint_as_float(((unsigned)(unsigned short)s) << 16);
}
static __device__ __forceinline__ unsigned fenc(float f) {
  unsigned u = __float_as_uint(f);
  return (u & 0x80000000u) ? ~u : (u | 0x80000000u);
}
static __device__ __forceinline__ float fdec(unsigned u) {
  u = (u & 0x80000000u) ? (u & 0x7fffffffu) : ~u;
  return __uint_as_float(u);
}

// ============ device bodies ============

// MFMA compute + epilogue shared by all GEMMs. As granule slot s of row holds
// source granule (s ^ (row&7)) of the current k-tile; compute reads slot
// (gb ^ (row&7)) to fetch granule gb. C/D layout col=lane&15, row=(lane>>4)*4+reg.
template <int KTILES, bool RELU, bool BIAS, bool GOUT>
static __device__ __forceinline__ void gemm_compute_epi(
    f32x4 (&acc)[2][8], const short* Wt, const float* bias, short* C16,
    const int* dstmap, int N, int n0, short* As, short* Ws, int kt, bool last) {
  const int tid = threadIdx.x;
  const int lane = tid & 63;
  const int w = tid >> 6;
  // stage W chunk (pre-swizzled, linear copy)
  const int4* wg = reinterpret_cast<const int4*>(Wt + kt * 128 * 64);
  int4* wl = reinterpret_cast<int4*>(Ws);
#pragma unroll
  for (int p = 0; p < 4; ++p) wl[p * 256 + tid] = wg[p * 256 + tid];
  __syncthreads();
#pragma unroll
  for (int kk = 0; kk < 2; ++kk) {
    int gb = kk * 4 + (lane >> 4);
    s16x8 a[2];
#pragma unroll
    for (int fr = 0; fr < 2; ++fr) {
      int row = w * 32 + fr * 16 + (lane & 15);
      a[fr] = *(const s16x8*)&As[(row * 8 + (gb ^ (row & 7))) * 8];
    }
#pragma unroll
    for (int fc = 0; fc < 8; ++fc) {
      int col = fc * 16 + (lane & 15);
      s16x8 b = *(const s16x8*)&Ws[(col * 8 + (gb ^ (col & 7))) * 8];
      acc[0][fc] = __builtin_amdgcn_mfma_f32_16x16x32_bf16(a[0], b, acc[0][fc], 0, 0, 0);
      acc[1][fc] = __builtin_amdgcn_mfma_f32_16x16x32_bf16(a[1], b, acc[1][fc], 0, 0, 0);
    }
  }
  if (!last) return;
  const int cb = lane & 15;
  const int rb = w * 32 + (lane >> 4) * 4;
#pragma unroll
  for (int fr = 0; fr < 2; ++fr) {
#pragma unroll
    for (int reg = 0; reg < 4; ++reg) {
      int n = n0 + rb + fr * 16 + reg;
      if (n >= N) continue;
      long drow = GOUT ? (long)dstmap[n] : (long)n;
      short* cp = C16 + drow * DIM;
#pragma unroll
      for (int fc = 0; fc < 8; ++fc) {
        float x = acc[fr][fc][reg];
        if (BIAS) x += bias[fc * 16 + cb];
        if (RELU) x = fmaxf(x, 0.f);
        cp[fc * 16 + cb] = f2bf(x);
      }
    }
  }
}

// fused segscatter+GEMM: tile row n = segment; A-staging computes
// sum_e w_e * IN16[row_e][k-slice] in fp32, rounds to bf16 (numerics == old path).
template <bool PACKEDIN, bool GOUT>
static __device__ __forceinline__ void fusedgemm_body(
    const int* __restrict__ ss, const int* __restrict__ sl,
    const int2* __restrict__ sedge, const short* __restrict__ IN16,
    const int* __restrict__ ro, const short* __restrict__ Wt,
    short* __restrict__ C16, const int* __restrict__ sd,
    const int* __restrict__ nsegp, short* As, short* Ws, int bid) {
  const int N = nsegp[0];
  const int n0 = bid * 128;
  if (n0 >= N) return;
  const int tid = threadIdx.x;
  f32x4 acc[2][8] = {};
#pragma unroll
  for (int kt = 0; kt < 2; ++kt) {
    __syncthreads();
#pragma unroll
    for (int p = 0; p < 4; ++p) {
      int gi = p * 256 + tid;
      int row = gi >> 3, s = gi & 7;
      int seg = n0 + row;
      s16x8 outv = {};
      if (seg < N) {
        int koff = kt * 64 + (s ^ (row & 7)) * 8;
        int st = ss[seg], len = sl[seg];
        float a0 = 0, a1 = 0, a2 = 0, a3 = 0, a4 = 0, a5 = 0, a6 = 0, a7 = 0;
        for (int e = st; e < st + len; ++e) {
          int2 v = sedge[e];
          int r2 = PACKEDIN ? ro[v.x] : v.x;
          if (PACKEDIN && r2 < 0) continue;
          float w = __int_as_float(v.y);
          s16x8 hv = *(const s16x8*)&IN16[(long)r2 * DIM + koff];
          a0 = fmaf(w, bf2f(hv[0]), a0); a1 = fmaf(w, bf2f(hv[1]), a1);
          a2 = fmaf(w, bf2f(hv[2]), a2); a3 = fmaf(w, bf2f(hv[3]), a3);
          a4 = fmaf(w, bf2f(hv[4]), a4); a5 = fmaf(w, bf2f(hv[5]), a5);
          a6 = fmaf(w, bf2f(hv[6]), a6); a7 = fmaf(w, bf2f(hv[7]), a7);
        }
        outv[0] = f2bf(a0); outv[1] = f2bf(a1); outv[2] = f2bf(a2); outv[3] = f2bf(a3);
        outv[4] = f2bf(a4); outv[5] = f2bf(a5); outv[6] = f2bf(a6); outv[7] = f2bf(a7);
      }
      *(s16x8*)&As[(row * 8 + s) * 8] = outv;
    }
    gemm_compute_epi<2, true, false, GOUT>(acc, Wt, nullptr, C16, sd, N, n0, As, Ws,
                                           kt, kt == 1);
  }
}

// table GEMM: table16[w] = wemb[w] @ WtAd + adb, fp32 input converted in staging
static __device__ __forceinline__ void tablegemm_body(
    const float* __restrict__ Af, const short* __restrict__ Wt,
    const float* __restrict__ bias, short* __restrict__ table16, short* As,
    short* Ws, int bid) {
  const int n0 = bid * 128;
  const int tid = threadIdx.x;
  f32x4 acc[2][8] = {};
#pragma unroll
  for (int kt = 0; kt < 4; ++kt) {
    __syncthreads();
#pragma unroll
    for (int p = 0; p < 4; ++p) {
      int gi = p * 256 + tid;
      int row = gi >> 3, s = gi & 7;
      int n = n0 + row;
      s16x8 v = {};
      if (n < NWORDS) {
        const float* ap = Af + (long)n * NINPK + kt * 64 + (s ^ (row & 7)) * 8;
        float4 v0 = *reinterpret_cast<const float4*>(ap);
        float4 v1 = *reinterpret_cast<const float4*>(ap + 4);
        v[0] = f2bf(v0.x); v[1] = f2bf(v0.y); v[2] = f2bf(v0.z); v[3] = f2bf(v0.w);
        v[4] = f2bf(v1.x); v[5] = f2bf(v1.y); v[6] = f2bf(v1.z); v[7] = f2bf(v1.w);
      }
      *(s16x8*)&As[(row * 8 + s) * 8] = v;
    }
    gemm_compute_epi<4, false, true, false>(acc, Wt, bias, table16, nullptr, NWORDS,
                                            n0, As, Ws, kt, kt == 3);
  }
}

// zero src-only touched hb rows
static __device__ __forceinline__ void zzero_body(short* __restrict__ hb,
                                                  const int* __restrict__ zl,
                                                  const int* __restrict__ nzp,
                                                  int bid, int nblocks) {
  int nz = nzp[0];
  int l = threadIdx.x & 31;
  s16x4 z = {};
  for (int s = bid * 8 + (threadIdx.x >> 5); s < nz; s += nblocks * 8) {
    *reinterpret_cast<s16x4*>(&hb[(long)zl[s] * DIM + l * 4]) = z;
  }
}

// fused LSTM step k (2 cols/block, 256 thr): gates, select, hx/cx update,
// writes bf16 weight tiles WtBase + layer*16384
static __device__ __forceinline__ void lstm_body(
    int bid, const float* __restrict__ hxc, float* __restrict__ hxn,
    float* __restrict__ cx, const float* __restrict__ Wih,
    const float* __restrict__ Whh, const float* __restrict__ bih,
    const float* __restrict__ bhh, const int* __restrict__ meta,
    short* __restrict__ WtBase, int k, float* wi, float* wh) {
  int tid = threadIdx.x;
  int i = bid >> 6;
  int j2 = bid & 63;
  int jl = tid >> 7;
  int r = tid & 127;
  int j = j2 * 2 + jl;
  float* wiL = wi + jl * 512;
  float* whL = wh + jl * 512;
#pragma unroll
  for (int g4 = 0; g4 < 4; ++g4) {
    wiL[g4 * 128 + r] = Wih[((long)i * 512 + g4 * 128 + j) * DIM + r];
    whL[g4 * 128 + r] = Whh[((long)i * 512 + g4 * 128 + j) * DIM + r];
  }
  __syncthreads();
  const float4* x4 = reinterpret_cast<const float4*>(hxc + ((long)i * DIM + r) * DIM);
  float a0 = 0, a1 = 0, a2 = 0, a3 = 0, b0 = 0, b1 = 0, b2 = 0, b3 = 0;
#pragma unroll 4
  for (int k4 = 0; k4 < 32; ++k4) {
    float4 xv = x4[k4];
    const float* vp = &xv.x;
#pragma unroll
    for (int q = 0; q < 4; ++q) {
      int kk = k4 * 4 + q;
      float xs = vp[q];
      a0 = fmaf(xs, wiL[kk], a0);       a1 = fmaf(xs, wiL[128 + kk], a1);
      a2 = fmaf(xs, wiL[256 + kk], a2); a3 = fmaf(xs, wiL[384 + kk], a3);
      b0 = fmaf(xs, whL[kk], b0);       b1 = fmaf(xs, whL[128 + kk], b1);
      b2 = fmaf(xs, whL[256 + kk], b2); b3 = fmaf(xs, whL[384 + kk], b3);
    }
  }
  int cbi = i * 512 + j;
  float g0i = a0 + bih[cbi] + bhh[cbi];
  float g0f = a1 + bih[cbi + 128] + bhh[cbi + 128];
  float g0g = a2 + bih[cbi + 256] + bhh[cbi + 256];
  float g0o = a3 + bih[cbi + 384] + bhh[cbi + 384];
  float g1i = g0i + b0, g1f = g0f + b1, g1g = g0g + b2, g1o = g0o + b3;
  int idx = i * 16384 + r * 128 + j;
  float c0v = cx[idx];
  float c_zero = sigm(g0i) * tanhf(g0g);
  float h_zero = sigm(g0o) * tanhf(c_zero);
  float c_st = sigm(g1f) * c0v + sigm(g1i) * tanhf(g1g);
  float h_st = sigm(g1o) * tanhf(c_st);
  int first = meta[8 + k];
  int has = meta[k] > 0;
  float hi_v = first ? h_st : h_zero;
  float ci_v = first ? c0v : c_zero;
  float xj = reinterpret_cast<const float*>(x4)[j];
  float hnew = has ? hi_v : xj;
  float cnew = has ? ci_v : c0v;
  hxn[idx] = hnew;
  cx[idx] = cnew;
  short* Wt = WtBase + i * 16384;
  int kb = r >> 6, g = (r >> 3) & 7, jj = r & 7;
  Wt[((kb * DIM + j) * 8 + (g ^ (j & 7))) * 8 + jj] = f2bf(hnew);
}

// ============ kernels ============

// setup0: init state/hist/flags/meta/keys + adaptW bf16 tiles
__global__ void k_setup0(const float* __restrict__ gcn, float* __restrict__ hxA,
                         float* __restrict__ cx, int* __restrict__ meta,
                         unsigned* __restrict__ keys, int* __restrict__ hist,
                         unsigned* __restrict__ flagbits,
                         const float* __restrict__ adW, short* __restrict__ WtAd) {
  int bid = blockIdx.x;
  int tid = threadIdx.x;
  if (bid < B_INITP) {
    int i = bid * 256 + tid;
    if (i < LLAYERS * DIM * DIM) { hxA[i] = gcn[i]; cx[i] = 0.f; }
    if (i < BGRAPH * DIM) keys[i] = 0u;
    if (i < 64) meta[i] = 0;
    if (i < NBINS) hist[i] = 0;
    if (i < (NBINS + 31) / 32) flagbits[i] = 0u;
  } else {
    int idx = (bid - B_INITP) * 256 + tid;  // < 4096
    int g = idx & 7;
    int c = (idx >> 3) & 127;
    int kb = idx >> 10;
    s16x8 s;
#pragma unroll
    for (int j = 0; j < 8; ++j) s[j] = f2bf(adW[(long)(kb * 64 + g * 8 + j) * DIM + c]);
    *(s16x8*)&WtAd[(((long)kb * DIM + c) * 8 + (g ^ (c & 7))) * 8] = s;
  }
}

// hist/flag atomics + table GEMM (fp32 wemb direct)
__global__ __launch_bounds__(256) void k_histg(
    const int* __restrict__ et, const int* __restrict__ src,
    const int* __restrict__ dst, int* __restrict__ hist,
    unsigned* __restrict__ flagbits, const float* __restrict__ wemb,
    const short* __restrict__ WtAd, const float* __restrict__ adb,
    short* __restrict__ table16) {
  __shared__ short As[128 * 64];
  __shared__ short Ws[128 * 64];
  int bid = blockIdx.x;
  if (bid < B_HIST) {
    int e = bid * 256 + threadIdx.x;
    if (e < E_EDGES) {
      int t = et[e];
      atomicAdd(&hist[t * N_NODES + dst[e]], 1);
      int fs = t * N_NODES + src[e];
      atomicOr(&flagbits[fs >> 5], 1u << (fs & 31));
    }
  } else {
    tablegemm_body(wemb, WtAd, adb, table16, As, Ws, bid - B_HIST);
  }
}

// fused 2-level exclusive scan: hist values, nonempty indicator, z indicator
__global__ void k_scan1b(const int* __restrict__ hist,
                         const unsigned* __restrict__ flagbits,
                         int* __restrict__ scanA, int* __restrict__ scanB,
                         int* __restrict__ scanC, int* __restrict__ bsumA,
                         int* __restrict__ bsumB, int* __restrict__ bsumC) {
  __shared__ int shA[256], shB[256], shC[256];
  int b0 = blockIdx.x * 1024;
  int tid = threadIdx.x;
  int v[4], w[4], z[4];
  int sA = 0, sB = 0, sC = 0;
#pragma unroll
  for (int q = 0; q < 4; ++q) {
    int i = b0 + tid * 4 + q;
    int c = (i < NBINS) ? hist[i] : 0;
    int fl = (i < NBINS) ? (int)((flagbits[i >> 5] >> (i & 31)) & 1u) : 0;
    v[q] = c; w[q] = (c > 0) ? 1 : 0; z[q] = (fl && c == 0) ? 1 : 0;
    sA += c; sB += w[q]; sC += z[q];
  }
  shA[tid] = sA; shB[tid] = sB; shC[tid] = sC;
  __syncthreads();
  for (int off = 1; off < 256; off <<= 1) {
    int xA = (tid >= off) ? shA[tid - off] : 0;
    int xB = (tid >= off) ? shB[tid - off] : 0;
    int xC = (tid >= off) ? shC[tid - off] : 0;
    __syncthreads();
    shA[tid] += xA; shB[tid] += xB; shC[tid] += xC;
    __syncthreads();
  }
  int exA = shA[tid] - sA, exB = shB[tid] - sB, exC = shC[tid] - sC;
#pragma unroll
  for (int q = 0; q < 4; ++q) {
    int i = b0 + tid * 4 + q;
    if (i < NBINS) { scanA[i] = exA; scanB[i] = exB; scanC[i] = exC; }
    exA += v[q]; exB += w[q]; exC += z[q];
  }
  if (tid == 255) {
    bsumA[blockIdx.x] = shA[255];
    bsumB[blockIdx.x] = shB[255];
    bsumC[blockIdx.x] = shC[255];
  }
}

// parallel block-sum scan (3 channels) + all meta fields
__global__ __launch_bounds__(256) void k_scan2p(
    int* __restrict__ bsumA, int* __restrict__ bsumB, int* __restrict__ bsumC,
    const int* __restrict__ scanA, const int* __restrict__ scanB,
    const int* __restrict__ scanC, int* __restrict__ meta) {
  __shared__ int pA[256], pB[256], pC[256];
  __shared__ int eA[512], eB[512], eC[512];
  int tid = threadIdx.x;
  int i0 = tid * 2, i1 = tid * 2 + 1;
  int a0 = (i0 < NB) ? bsumA[i0] : 0, a1 = (i1 < NB) ? bsumA[i1] : 0;
  int b0 = (i0 < NB) ? bsumB[i0] : 0, b1 = (i1 < NB) ? bsumB[i1] : 0;
  int c0 = (i0 < NB) ? bsumC[i0] : 0, c1 = (i1 < NB) ? bsumC[i1] : 0;
  int tA = a0 + a1, tB = b0 + b1, tC = c0 + c1;
  pA[tid] = tA; pB[tid] = tB; pC[tid] = tC;
  __syncthreads();
  for (int off = 1; off < 256; off <<= 1) {
    int xA = (tid >= off) ? pA[tid - off] : 0;
    int xB = (tid >= off) ? pB[tid - off] : 0;
    int xC = (tid >= off) ? pC[tid - off] : 0;
    __syncthreads();
    pA[tid] += xA; pB[tid] += xB; pC[tid] += xC;
    __syncthreads();
  }
  int baseA = pA[tid] - tA, baseB = pB[tid] - tB, baseC = pC[tid] - tC;
  eA[i0] = baseA; eA[i1] = baseA + a0;
  eB[i0] = baseB; eB[i1] = baseB + b0;
  eC[i0] = baseC; eC[i1] = baseC + c0;
  if (i0 < NB) { bsumA[i0] = baseA; bsumB[i0] = baseB; bsumC[i0] = baseC; }
  if (i1 < NB) { bsumA[i1] = baseA + a0; bsumB[i1] = baseB + b0; bsumC[i1] = baseC + c0; }
  __syncthreads();
  if (tid == 0) {
    int loA[TSTEPS + 1], loB[TSTEPS + 1], loC[TSTEPS + 1];
    for (int t = 0; t < TSTEPS; ++t) {
      int ib = t * N_NODES, blk = ib >> 10;
      loA[t] = scanA[ib] + eA[blk];
      loB[t] = scanB[ib] + eB[blk];
      loC[t] = scanC[ib] + eC[blk];
    }
    loA[TSTEPS] = pA[255]; loB[TSTEPS] = pB[255]; loC[TSTEPS] = pC[255];
    int f = 0;
    for (int t = 0; t < TSTEPS; ++t) {
      int cnt = loA[t + 1] - loA[t];
      meta[t] = cnt;
      meta[8 + t] = f; f |= (cnt > 0);
      meta[32 + t] = loB[t + 1] - loB[t];   // segcnt
      meta[48 + t] = loB[t];                // seg rank base
      meta[40 + t] = loC[t + 1] - loC[t];   // zcnt
      meta[56 + t] = loC[t];                // z rank base
    }
  }
}

// finalize scan; build segments + rowof (+ -1 fill) + zlist via scan ranks
__global__ void k_scan3seg(int* __restrict__ scanA, const int* __restrict__ bsumA,
                           const int* __restrict__ scanB, const int* __restrict__ bsumB,
                           const int* __restrict__ scanC, const int* __restrict__ bsumC,
                           const int* __restrict__ hist,
                           const unsigned* __restrict__ flagbits,
                           const int* __restrict__ meta, int* __restrict__ segdst,
                           int* __restrict__ segstart, int* __restrict__ seglen,
                           int* __restrict__ rowof, int* __restrict__ zlist) {
  int i = blockIdx.x * blockDim.x + threadIdx.x;
  if (i >= NBINS) return;
  int vA = scanA[i] + bsumA[i >> 10];
  scanA[i] = vA;
  int c = hist[i];
  int t = i / N_NODES;
  int tb = t * N_NODES;
  if (c > 0) {
    int sidx = scanB[i] + bsumB[i >> 10] - meta[48 + t];
    long sb = (long)tb + sidx;
    segdst[sb] = i - tb;
    segstart[sb] = vA;
    seglen[sb] = c;
    rowof[i] = sidx;
  } else {
    rowof[i] = -1;
    if ((flagbits[i >> 5] >> (i & 31)) & 1u) {
      int zr = scanC[i] + bsumC[i >> 10] - meta[56 + t];
      zlist[(long)tb + zr] = i - tb;
    }
  }
}

// setup1: place edges + embed gather + lstm(0)
__global__ __launch_bounds__(256) void k_setup1(
    const int* __restrict__ et, const int* __restrict__ src,
    const int* __restrict__ dst, const float* __restrict__ ew,
    int* __restrict__ scanA, int2* __restrict__ sedge,
    const short* __restrict__ table16, const int* __restrict__ wid,
    short* __restrict__ hb, const float* __restrict__ hxA, float* __restrict__ hxB,
    float* __restrict__ cx, const float* __restrict__ Wih,
    const float* __restrict__ Whh, const float* __restrict__ bih,
    const float* __restrict__ bhh, const int* __restrict__ meta,
    short* __restrict__ WtT) {
  __shared__ float lb[2048];
  int bid = blockIdx.x;
  int tid = threadIdx.x;
  if (bid < B_PLACE) {
    int e = bid * 256 + tid;
    if (e < E_EDGES) {
      int t = et[e];
      int bin = t * N_NODES + dst[e];
      int pos = atomicAdd(&scanA[bin], 1);
      sedge[pos] = make_int2(src[e], __float_as_int(ew[e]));
    }
  } else if (bid < B_PLACE + B_EMBED) {
    int l = tid & 31;
    for (int n = (bid - B_PLACE) * 8 + (tid >> 5); n < N_NODES; n += B_EMBED * 8) {
      *reinterpret_cast<s16x4*>(&hb[(long)n * DIM + l * 4]) =
          *reinterpret_cast<const s16x4*>(&table16[(long)wid[n] * DIM + l * 4]);
    }
  } else {
    lstm_body(bid - B_PLACE - B_EMBED, hxA, hxB, cx, Wih, Whh, bih, bhh, meta,
              WtT, 0, lb, lb + 1024);
  }
}

// loop launch A: fused scat0+gemm0 (P2b = relu(segsum(hb) @ WtT[t][0])) ∥ lstm(t+1)
__global__ __launch_bounds__(256) void k_A(
    const int* __restrict__ ss, const int* __restrict__ sl,
    const int2* __restrict__ sedge, const short* __restrict__ hb,
    const short* __restrict__ Wt0, short* __restrict__ P2b,
    const int* __restrict__ nsegp, const float* __restrict__ hxc,
    float* __restrict__ hxn, float* __restrict__ cx,
    const float* __restrict__ Wih, const float* __restrict__ Whh,
    const float* __restrict__ bih, const float* __restrict__ bhh,
    const int* __restrict__ meta, short* __restrict__ WtNext, int k) {
  __shared__ short As[128 * 64];
  __shared__ short Ws[128 * 64];
  int bid = blockIdx.x;
  if (bid < GB) {
    fusedgemm_body<false, false>(ss, sl, sedge, hb, nullptr, Wt0, P2b, nullptr,
                                 nsegp, As, Ws, bid);
  } else if (k < TSTEPS) {
    float* lb = (float*)As;
    lstm_body(bid - GB, hxc, hxn, cx, Wih, Whh, bih, bhh, meta, WtNext, k,
              lb, lb + 1024);
  }
}

// loop launch B: fused scat1+gemm1 (hb[segdst] = relu(segsum(P2b) @ WtT[t][1])) ∥ zzero
__global__ __launch_bounds__(256) void k_B(
    const int* __restrict__ ss, const int* __restrict__ sl,
    const int2* __restrict__ sedge, const short* __restrict__ P2b,
    const int* __restrict__ ro, const short* __restrict__ Wt1,
    short* __restrict__ hb, const int* __restrict__ sd,
    const int* __restrict__ nsegp, const int* __restrict__ zl,
    const int* __restrict__ nzp) {
  __shared__ short As[128 * 64];
  __shared__ short Ws[128 * 64];
  int bid = blockIdx.x;
  if (bid < GB) {
    fusedgemm_body<true, true>(ss, sl, sedge, P2b, ro, Wt1, hb, sd, nsegp,
                               As, Ws, bid);
  } else {
    zzero_body(hb, zl, nzp, bid - GB, B_ZZ);
  }
}

// segment max + fused final (last block via completion counter)
__global__ void k_segmax(const short* __restrict__ hb, const int* __restrict__ gid,
                         unsigned* __restrict__ keys, const float* __restrict__ outW,
                         const float* __restrict__ outB, const float* __restrict__ y,
                         float* __restrict__ out, int* __restrict__ counter) {
  __shared__ float lt[BGRAPH];
  __shared__ int lastflag;
  int d = threadIdx.x;
  int n0 = blockIdx.x * 64;
  int end = min(n0 + 64, N_NODES);
  int curg = gid[n0];
  float m = -INFINITY;
  for (int n = n0; n < end; ++n) {
    int g = gid[n];
    if (g != curg) {
      atomicMax(&keys[(long)curg * DIM + d], fenc(m));
      curg = g;
      m = -INFINITY;
    }
    m = fmaxf(m, bf2f(hb[(long)n * DIM + d]));
  }
  atomicMax(&keys[(long)curg * DIM + d], fenc(m));
  __threadfence();
  __syncthreads();
  if (threadIdx.x == 0) {
    int c = atomicAdd(counter, 1);
    lastflag = (c == gridDim.x - 1);
  }
  __syncthreads();
  if (lastflag) {
    __threadfence();
    int tid = threadIdx.x;
    if (tid < 64) {
      int b = tid >> 2, l4 = tid & 3;
      float s = 0.f;
      for (int dd = l4; dd < DIM; dd += 4) {
        unsigned kv = atomicOr(&keys[(long)b * DIM + dd], 0u);  // L2-coherent read
        float v = fdec(kv);
        if (!isfinite(v)) v = 0.f;
        s += v * outW[dd];
      }
      s += __shfl_down(s, 1);
      s += __shfl_down(s, 2);
      if (l4 == 0) {
        float l = s + outB[0];
        out[1 + b] = 1.f / (1.f + expf(-l));
        lt[b] = fmaxf(l, 0.f) - l * y[b] + log1pf(expf(-fabsf(l)));
      }
    }
    __syncthreads();
    if (tid == 0) {
      float acc = 0.f;
      for (int i = 0; i < BGRAPH; ++i) acc += lt[i];
      out[0] = acc / (float)BGRAPH;
    }
  }
}

extern "C" void kernel_launch(void* const* d_in, const int* in_sizes, int n_in,
                              void* d_out, int out_size, void* d_ws, size_t ws_size,
                              hipStream_t stream) {
  const int* word_ids = (const int*)d_in[0];
  const int* src = (const int*)d_in[1];
  const int* dst = (const int*)d_in[2];
  const int* et = (const int*)d_in[3];
  const float* ew = (const float*)d_in[4];
  const int* gid = (const int*)d_in[5];
  const float* y = (const float*)d_in[6];
  const float* wemb = (const float*)d_in[7];
  const float* adW = (const float*)d_in[8];
  const float* adb = (const float*)d_in[9];
  const float* gcn = (const float*)d_in[10];
  const float* Wih = (const float*)d_in[11];
  const float* Whh = (const float*)d_in[12];
  const float* bih = (const float*)d_in[13];
  const float* bhh = (const float*)d_in[14];
  const float* outW = (const float*)d_in[15];
  const float* outB = (const float*)d_in[16];
  float* out = (float*)d_out;

  char* ws = (char*)d_ws;
  const long ND = (long)N_NODES * DIM;
  short* hb = (short*)ws;       ws += ND * 2;
  short* P2b = (short*)ws;      ws += ND * 2;
  float* hxA = (float*)ws;      ws += LLAYERS * DIM * DIM * 4;
  float* hxB = (float*)ws;      ws += LLAYERS * DIM * DIM * 4;
  float* cx = (float*)ws;       ws += LLAYERS * DIM * DIM * 4;
  int* meta = (int*)ws;         ws += 64 * 4;
  unsigned* keys = (unsigned*)ws; ws += BGRAPH * DIM * 4;
  int* hist = (int*)ws;         ws += (long)NBINS * 4;
  int* scanA = (int*)ws;        ws += (long)NBINS * 4;
  int* scanB = (int*)ws;        ws += (long)NBINS * 4;
  int* scanC = (int*)ws;        ws += (long)NBINS * 4;
  int* bsumA = (int*)ws;        ws += ((NB + 63) & ~63) * 4;
  int* bsumB = (int*)ws;        ws += ((NB + 63) & ~63) * 4;
  int* bsumC = (int*)ws;        ws += ((NB + 63) & ~63) * 4;
  int* rowof = (int*)ws;        ws += (long)NBINS * 4;
  int* segdst = (int*)ws;       ws += (long)NBINS * 4;
  int* segstart = (int*)ws;     ws += (long)NBINS * 4;
  int* seglen = (int*)ws;       ws += (long)NBINS * 4;
  int* zlist = (int*)ws;        ws += (long)NBINS * 4;
  int2* sedge = (int2*)ws;      ws += (long)E_EDGES * 8;
  unsigned* flagbits = (unsigned*)ws; ws += ((NBINS + 31) / 32 + 64) * 4;
  short* table16 = (short*)ws;  ws += (long)NWORDS * DIM * 2;
  short* WtAd = (short*)ws;     ws += 4L * DIM * 64 * 2;
  short* WtT = (short*)ws;      ws += 7L * 2 * 16384 * 2;  // [t][layer] bf16 tiles

  // ---- setup (6 launches) ----
  k_setup0<<<B_INITP + B_PREP, 256, 0, stream>>>(gcn, hxA, cx, meta, keys, hist,
                                                 flagbits, adW, WtAd);
  k_histg<<<B_HIST + B_TGEMM, 256, 0, stream>>>(et, src, dst, hist, flagbits,
                                                wemb, WtAd, adb, table16);
  k_scan1b<<<NB, 256, 0, stream>>>(hist, flagbits, scanA, scanB, scanC,
                                   bsumA, bsumB, bsumC);
  k_scan2p<<<1, 256, 0, stream>>>(bsumA, bsumB, bsumC, scanA, scanB, scanC, meta);
  k_scan3seg<<<B_INITP, 256, 0, stream>>>(scanA, bsumA, scanB, bsumB, scanC, bsumC,
                                          hist, flagbits, meta, segdst, segstart,
                                          seglen, rowof, zlist);
  k_setup1<<<B_PLACE + B_EMBED + B_LSTM, 256, 0, stream>>>(
      et, src, dst, ew, scanA, sedge, table16, word_ids, hb, hxA, hxB, cx,
      Wih, Whh, bih, bhh, meta, WtT);

  // ---- t-loop (2 launches per step) ----
  for (int t = 0; t < TSTEPS; ++t) {
    const int* nsegp = &meta[32 + t];
    const int* nzp = &meta[40 + t];
    const int* ss = segstart + (long)t * N_NODES;
    const int* sl = seglen + (long)t * N_NODES;
    const int* sd = segdst + (long)t * N_NODES;
    const int* ro = rowof + (long)t * N_NODES;
    const int* zl = zlist + (long)t * N_NODES;
    int k = t + 1;  // prefetched lstm step
    const float* hxc = (k & 1) ? hxB : hxA;
    float* hxn = (k & 1) ? hxA : hxB;
    k_A<<<GB + B_LSTM, 256, 0, stream>>>(
        ss, sl, sedge, hb, WtT + (long)t * 2 * 16384, P2b, nsegp,
        hxc, hxn, cx, Wih, Whh, bih, bhh, meta, WtT + (long)k * 2 * 16384, k);
    k_B<<<GB + B_ZZ, 256, 0, stream>>>(
        ss, sl, sedge, P2b, ro, WtT + ((long)t * 2 + 1) * 16384, hb, sd, nsegp,
        zl, nzp);
  }

  k_segmax<<<B_SEGMAX, 128, 0, stream>>>(hb, gid, keys, outW, outB, y, out,
                                         &meta[62]);
}

// Round 10
// 373.243 us; speedup vs baseline: 1.0813x; 1.0813x over previous
//
#include <hip/hip_runtime.h>
#include <hip/hip_bf16.h>
#include <math.h>

#define N_NODES 60000
#define E_EDGES 200000
#define DIM     128
#define NINPK   256
#define TSTEPS  6
#define LLAYERS 2
#define BGRAPH  16
#define NBINS   (TSTEPS * N_NODES)          // 360000
#define NB      ((NBINS + 1023) / 1024)     // 352 scan blocks
#define NWORDS  15000

#define B_INITP  ((NBINS + 255) / 256)          // 1407
#define B_PREP   16
#define B_HIST   ((E_EDGES + 255) / 256)        // 782
#define B_TGEMM  ((NWORDS + 127) / 128)         // 118
#define B_PLACE  ((E_EDGES + 255) / 256)        // 782
#define B_EMBED  512
#define B_LSTM   128
#define GB       ((N_NODES + 127) / 128)        // 469 (dyn early-exit on nseg)
#define B_ZZ     64
#define B_SEGMAX ((N_NODES + 127) / 128)        // 469

typedef float f32x4 __attribute__((ext_vector_type(4)));
typedef short s16x8 __attribute__((ext_vector_type(8)));
typedef short s16x4 __attribute__((ext_vector_type(4)));

static __device__ __forceinline__ float sigm(float x) { return 1.f / (1.f + expf(-x)); }

static __device__ __forceinline__ short f2bf(float f) {
  unsigned u = __float_as_uint(f);
  u += 0x7FFFu + ((u >> 16) & 1u);
  return (short)(u >> 16);
}
static __device__ __forceinline__ float bf2f(short s) {
  return __uint_as_float(((unsigned)(unsigned short)s) << 16);
}
static __device__ __forceinline__ unsigned fenc(float f) {
  unsigned u = __float_as_uint(f);
  return (u & 0x80000000u) ? ~u : (u | 0x80000000u);
}
static __device__ __forceinline__ float fdec(unsigned u) {
  u = (u & 0x80000000u) ? (u & 0x7fffffffu) : ~u;
  return __uint_as_float(u);
}

// ============ device bodies ============

// W-stage + MFMA + optional epilogue. As granule address:
// (row * rsg + ktg + (gb ^ (row&7))) * 8. Includes leading barrier ordering
// prior As/As2 writes (and prior-iteration Ws reads) before Ws restage.
template <bool RELU, bool BIAS, bool GOUT>
static __device__ __forceinline__ void gemm_compute_epi(
    f32x4 (&acc)[2][8], const short* WtKt, const float* bias, short* C16,
    const int* dstmap, int N, int n0, const short* As, int rsg, int ktg,
    short* Ws, bool last) {
  const int tid = threadIdx.x;
  const int lane = tid & 63;
  const int w = tid >> 6;
  __syncthreads();
  const int4* wg = reinterpret_cast<const int4*>(WtKt);
  int4* wl = reinterpret_cast<int4*>(Ws);
#pragma unroll
  for (int p = 0; p < 4; ++p) wl[p * 256 + tid] = wg[p * 256 + tid];
  __syncthreads();
#pragma unroll
  for (int kk = 0; kk < 2; ++kk) {
    int gb = kk * 4 + (lane >> 4);
    s16x8 a[2];
#pragma unroll
    for (int fr = 0; fr < 2; ++fr) {
      int row = w * 32 + fr * 16 + (lane & 15);
      a[fr] = *(const s16x8*)&As[(row * rsg + ktg + (gb ^ (row & 7))) * 8];
    }
#pragma unroll
    for (int fc = 0; fc < 8; ++fc) {
      int col = fc * 16 + (lane & 15);
      s16x8 b = *(const s16x8*)&Ws[(col * 8 + (gb ^ (col & 7))) * 8];
      acc[0][fc] = __builtin_amdgcn_mfma_f32_16x16x32_bf16(a[0], b, acc[0][fc], 0, 0, 0);
      acc[1][fc] = __builtin_amdgcn_mfma_f32_16x16x32_bf16(a[1], b, acc[1][fc], 0, 0, 0);
    }
  }
  if (!last) return;
  // epilogue: C/D layout col=lane&15, row=(lane>>4)*4+reg  [m89-verified]
  const int cb = lane & 15;
  const int rb = w * 32 + (lane >> 4) * 4;
#pragma unroll
  for (int fr = 0; fr < 2; ++fr) {
#pragma unroll
    for (int reg = 0; reg < 4; ++reg) {
      int n = n0 + rb + fr * 16 + reg;
      if (n >= N) continue;
      long drow = GOUT ? (long)dstmap[n] : (long)n;
      short* cp = C16 + drow * DIM;
#pragma unroll
      for (int fc = 0; fc < 8; ++fc) {
        float x = acc[fr][fc][reg];
        if (BIAS) x += bias[fc * 16 + cb];
        if (RELU) x = fmaxf(x, 0.f);
        cp[fc * 16 + cb] = f2bf(x);
      }
    }
  }
}

// fused segscatter+GEMM, two-phase: (0) 16-lane groups scatter segment-sums
// into As2[128][128] (sedge broadcast once per group, coalesced 256B row
// gathers), (1) two k-tile MFMA passes out of As2. Numerics == old path.
template <bool PACKEDIN, bool GOUT>
static __device__ __forceinline__ void fusedgemm_body(
    const int* __restrict__ ss, const int* __restrict__ sl,
    const int2* __restrict__ sedge, const short* __restrict__ IN16,
    const int* __restrict__ ro, const short* __restrict__ Wt,
    short* __restrict__ C16, const int* __restrict__ sd,
    const int* __restrict__ nsegp, short* As2, short* Ws, int bid) {
  const int N = nsegp[0];
  const int n0 = bid * 128;
  if (n0 >= N) return;
  const int tid = threadIdx.x;
  const int lane16 = tid & 15;
  const int grp = tid >> 4;
#pragma unroll
  for (int it = 0; it < 8; ++it) {
    int row = it * 16 + grp;
    int seg = n0 + row;
    float a0 = 0, a1 = 0, a2 = 0, a3 = 0, a4 = 0, a5 = 0, a6 = 0, a7 = 0;
    if (seg < N) {
      int st = ss[seg], en = st + sl[seg];
      for (int e = st; e < en; ++e) {
        int2 v = sedge[e];
        int r2 = PACKEDIN ? ro[v.x] : v.x;
        if (PACKEDIN && r2 < 0) continue;
        float w = __int_as_float(v.y);
        s16x8 hv = *(const s16x8*)&IN16[(long)r2 * DIM + lane16 * 8];
        a0 = fmaf(w, bf2f(hv[0]), a0); a1 = fmaf(w, bf2f(hv[1]), a1);
        a2 = fmaf(w, bf2f(hv[2]), a2); a3 = fmaf(w, bf2f(hv[3]), a3);
        a4 = fmaf(w, bf2f(hv[4]), a4); a5 = fmaf(w, bf2f(hv[5]), a5);
        a6 = fmaf(w, bf2f(hv[6]), a6); a7 = fmaf(w, bf2f(hv[7]), a7);
      }
    }
    s16x8 outv;
    outv[0] = f2bf(a0); outv[1] = f2bf(a1); outv[2] = f2bf(a2); outv[3] = f2bf(a3);
    outv[4] = f2bf(a4); outv[5] = f2bf(a5); outv[6] = f2bf(a6); outv[7] = f2bf(a7);
    int slot = (lane16 & 8) | ((lane16 & 7) ^ (row & 7));
    *(s16x8*)&As2[(row * 16 + slot) * 8] = outv;
  }
  f32x4 acc[2][8] = {};
#pragma unroll
  for (int kt = 0; kt < 2; ++kt) {
    gemm_compute_epi<true, false, GOUT>(acc, Wt + kt * 128 * 64, nullptr, C16, sd,
                                        N, n0, As2, 16, kt * 8, Ws, kt == 1);
  }
}

// table GEMM: table16[w] = wemb[w] @ WtAd + adb (fp32 converted in staging)
static __device__ __forceinline__ void tablegemm_body(
    const float* __restrict__ Af, const short* __restrict__ Wt,
    const float* __restrict__ bias, short* __restrict__ table16, short* As,
    short* Ws, int bid) {
  const int n0 = bid * 128;
  const int tid = threadIdx.x;
  f32x4 acc[2][8] = {};
#pragma unroll
  for (int kt = 0; kt < 4; ++kt) {
    __syncthreads();  // prior MFMA reads of As done before restage
#pragma unroll
    for (int p = 0; p < 4; ++p) {
      int gi = p * 256 + tid;
      int row = gi >> 3, s = gi & 7;
      int n = n0 + row;
      s16x8 v = {};
      if (n < NWORDS) {
        const float* ap = Af + (long)n * NINPK + kt * 64 + (s ^ (row & 7)) * 8;
        float4 v0 = *reinterpret_cast<const float4*>(ap);
        float4 v1 = *reinterpret_cast<const float4*>(ap + 4);
        v[0] = f2bf(v0.x); v[1] = f2bf(v0.y); v[2] = f2bf(v0.z); v[3] = f2bf(v0.w);
        v[4] = f2bf(v1.x); v[5] = f2bf(v1.y); v[6] = f2bf(v1.z); v[7] = f2bf(v1.w);
      }
      *(s16x8*)&As[(row * 8 + s) * 8] = v;
    }
    gemm_compute_epi<false, true, false>(acc, Wt + kt * 128 * 64, bias, table16,
                                         nullptr, NWORDS, n0, As, 8, 0, Ws, kt == 3);
  }
}

// zero src-only touched hb rows
static __device__ __forceinline__ void zzero_body(short* __restrict__ hb,
                                                  const int* __restrict__ zl,
                                                  const int* __restrict__ nzp,
                                                  int bid, int nblocks) {
  int nz = nzp[0];
  int l = threadIdx.x & 31;
  s16x4 z = {};
  for (int s = bid * 8 + (threadIdx.x >> 5); s < nz; s += nblocks * 8) {
    *reinterpret_cast<s16x4*>(&hb[(long)zl[s] * DIM + l * 4]) = z;
  }
}

// fused LSTM step k (2 cols/block, 256 thr): gates, select, hx/cx update,
// writes bf16 weight tiles WtBase + layer*16384
static __device__ __forceinline__ void lstm_body(
    int bid, const float* __restrict__ hxc, float* __restrict__ hxn,
    float* __restrict__ cx, const float* __restrict__ Wih,
    const float* __restrict__ Whh, const float* __restrict__ bih,
    const float* __restrict__ bhh, const int* __restrict__ meta,
    short* __restrict__ WtBase, int k, float* wi, float* wh) {
  int tid = threadIdx.x;
  int i = bid >> 6;
  int j2 = bid & 63;
  int jl = tid >> 7;
  int r = tid & 127;
  int j = j2 * 2 + jl;
  float* wiL = wi + jl * 512;
  float* whL = wh + jl * 512;
#pragma unroll
  for (int g4 = 0; g4 < 4; ++g4) {
    wiL[g4 * 128 + r] = Wih[((long)i * 512 + g4 * 128 + j) * DIM + r];
    whL[g4 * 128 + r] = Whh[((long)i * 512 + g4 * 128 + j) * DIM + r];
  }
  __syncthreads();
  const float4* x4 = reinterpret_cast<const float4*>(hxc + ((long)i * DIM + r) * DIM);
  float a0 = 0, a1 = 0, a2 = 0, a3 = 0, b0 = 0, b1 = 0, b2 = 0, b3 = 0;
#pragma unroll 4
  for (int k4 = 0; k4 < 32; ++k4) {
    float4 xv = x4[k4];
    const float* vp = &xv.x;
#pragma unroll
    for (int q = 0; q < 4; ++q) {
      int kk = k4 * 4 + q;
      float xs = vp[q];
      a0 = fmaf(xs, wiL[kk], a0);       a1 = fmaf(xs, wiL[128 + kk], a1);
      a2 = fmaf(xs, wiL[256 + kk], a2); a3 = fmaf(xs, wiL[384 + kk], a3);
      b0 = fmaf(xs, whL[kk], b0);       b1 = fmaf(xs, whL[128 + kk], b1);
      b2 = fmaf(xs, whL[256 + kk], b2); b3 = fmaf(xs, whL[384 + kk], b3);
    }
  }
  int cbi = i * 512 + j;
  float g0i = a0 + bih[cbi] + bhh[cbi];
  float g0f = a1 + bih[cbi + 128] + bhh[cbi + 128];
  float g0g = a2 + bih[cbi + 256] + bhh[cbi + 256];
  float g0o = a3 + bih[cbi + 384] + bhh[cbi + 384];
  float g1i = g0i + b0, g1f = g0f + b1, g1g = g0g + b2, g1o = g0o + b3;
  int idx = i * 16384 + r * 128 + j;
  float c0v = cx[idx];
  float c_zero = sigm(g0i) * tanhf(g0g);
  float h_zero = sigm(g0o) * tanhf(c_zero);
  float c_st = sigm(g1f) * c0v + sigm(g1i) * tanhf(g1g);
  float h_st = sigm(g1o) * tanhf(c_st);
  int first = meta[8 + k];
  int has = meta[k] > 0;
  float hi_v = first ? h_st : h_zero;
  float ci_v = first ? c0v : c_zero;
  float xj = reinterpret_cast<const float*>(x4)[j];
  float hnew = has ? hi_v : xj;
  float cnew = has ? ci_v : c0v;
  hxn[idx] = hnew;
  cx[idx] = cnew;
  short* Wt = WtBase + i * 16384;
  int kb = r >> 6, g = (r >> 3) & 7, jj = r & 7;
  Wt[((kb * DIM + j) * 8 + (g ^ (j & 7))) * 8 + jj] = f2bf(hnew);
}

// ============ kernels ============

// setup0: init state/hist/flags/meta/keys + adaptW bf16 tiles
__global__ void k_setup0(const float* __restrict__ gcn, float* __restrict__ hxA,
                         float* __restrict__ cx, int* __restrict__ meta,
                         unsigned* __restrict__ keys, int* __restrict__ hist,
                         unsigned* __restrict__ flagbits,
                         const float* __restrict__ adW, short* __restrict__ WtAd) {
  int bid = blockIdx.x;
  int tid = threadIdx.x;
  if (bid < B_INITP) {
    int i = bid * 256 + tid;
    if (i < LLAYERS * DIM * DIM) { hxA[i] = gcn[i]; cx[i] = 0.f; }
    if (i < BGRAPH * DIM) keys[i] = 0u;
    if (i < 64) meta[i] = 0;
    if (i < NBINS) hist[i] = 0;
    if (i < (NBINS + 31) / 32) flagbits[i] = 0u;
  } else {
    int idx = (bid - B_INITP) * 256 + tid;  // < 4096
    int g = idx & 7;
    int c = (idx >> 3) & 127;
    int kb = idx >> 10;
    s16x8 s;
#pragma unroll
    for (int j = 0; j < 8; ++j) s[j] = f2bf(adW[(long)(kb * 64 + g * 8 + j) * DIM + c]);
    *(s16x8*)&WtAd[(((long)kb * DIM + c) * 8 + (g ^ (c & 7))) * 8] = s;
  }
}

// hist/flag atomics + table GEMM (fp32 wemb direct)
__global__ __launch_bounds__(256) void k_histg(
    const int* __restrict__ et, const int* __restrict__ src,
    const int* __restrict__ dst, int* __restrict__ hist,
    unsigned* __restrict__ flagbits, const float* __restrict__ wemb,
    const short* __restrict__ WtAd, const float* __restrict__ adb,
    short* __restrict__ table16) {
  __shared__ short As[128 * 64];
  __shared__ short Ws[128 * 64];
  int bid = blockIdx.x;
  if (bid < B_HIST) {
    int e = bid * 256 + threadIdx.x;
    if (e < E_EDGES) {
      int t = et[e];
      atomicAdd(&hist[t * N_NODES + dst[e]], 1);
      int fs = t * N_NODES + src[e];
      atomicOr(&flagbits[fs >> 5], 1u << (fs & 31));
    }
  } else {
    tablegemm_body(wemb, WtAd, adb, table16, As, Ws, bid - B_HIST);
  }
}

// fused 2-level exclusive scan: hist values, nonempty indicator, z indicator
__global__ void k_scan1b(const int* __restrict__ hist,
                         const unsigned* __restrict__ flagbits,
                         int* __restrict__ scanA, int* __restrict__ scanB,
                         int* __restrict__ scanC, int* __restrict__ bsumA,
                         int* __restrict__ bsumB, int* __restrict__ bsumC) {
  __shared__ int shA[256], shB[256], shC[256];
  int b0 = blockIdx.x * 1024;
  int tid = threadIdx.x;
  int v[4], w[4], z[4];
  int sA = 0, sB = 0, sC = 0;
#pragma unroll
  for (int q = 0; q < 4; ++q) {
    int i = b0 + tid * 4 + q;
    int c = (i < NBINS) ? hist[i] : 0;
    int fl = (i < NBINS) ? (int)((flagbits[i >> 5] >> (i & 31)) & 1u) : 0;
    v[q] = c; w[q] = (c > 0) ? 1 : 0; z[q] = (fl && c == 0) ? 1 : 0;
    sA += c; sB += w[q]; sC += z[q];
  }
  shA[tid] = sA; shB[tid] = sB; shC[tid] = sC;
  __syncthreads();
  for (int off = 1; off < 256; off <<= 1) {
    int xA = (tid >= off) ? shA[tid - off] : 0;
    int xB = (tid >= off) ? shB[tid - off] : 0;
    int xC = (tid >= off) ? shC[tid - off] : 0;
    __syncthreads();
    shA[tid] += xA; shB[tid] += xB; shC[tid] += xC;
    __syncthreads();
  }
  int exA = shA[tid] - sA, exB = shB[tid] - sB, exC = shC[tid] - sC;
#pragma unroll
  for (int q = 0; q < 4; ++q) {
    int i = b0 + tid * 4 + q;
    if (i < NBINS) { scanA[i] = exA; scanB[i] = exB; scanC[i] = exC; }
    exA += v[q]; exB += w[q]; exC += z[q];
  }
  if (tid == 255) {
    bsumA[blockIdx.x] = shA[255];
    bsumB[blockIdx.x] = shB[255];
    bsumC[blockIdx.x] = shC[255];
  }
}

// parallel block-sum scan (3 channels) + all meta fields
__global__ __launch_bounds__(256) void k_scan2p(
    int* __restrict__ bsumA, int* __restrict__ bsumB, int* __restrict__ bsumC,
    const int* __restrict__ scanA, const int* __restrict__ scanB,
    const int* __restrict__ scanC, int* __restrict__ meta) {
  __shared__ int pA[256], pB[256], pC[256];
  __shared__ int eA[512], eB[512], eC[512];
  int tid = threadIdx.x;
  int i0 = tid * 2, i1 = tid * 2 + 1;
  int a0 = (i0 < NB) ? bsumA[i0] : 0, a1 = (i1 < NB) ? bsumA[i1] : 0;
  int b0 = (i0 < NB) ? bsumB[i0] : 0, b1 = (i1 < NB) ? bsumB[i1] : 0;
  int c0 = (i0 < NB) ? bsumC[i0] : 0, c1 = (i1 < NB) ? bsumC[i1] : 0;
  int tA = a0 + a1, tB = b0 + b1, tC = c0 + c1;
  pA[tid] = tA; pB[tid] = tB; pC[tid] = tC;
  __syncthreads();
  for (int off = 1; off < 256; off <<= 1) {
    int xA = (tid >= off) ? pA[tid - off] : 0;
    int xB = (tid >= off) ? pB[tid - off] : 0;
    int xC = (tid >= off) ? pC[tid - off] : 0;
    __syncthreads();
    pA[tid] += xA; pB[tid] += xB; pC[tid] += xC;
    __syncthreads();
  }
  int baseA = pA[tid] - tA, baseB = pB[tid] - tB, baseC = pC[tid] - tC;
  eA[i0] = baseA; eA[i1] = baseA + a0;
  eB[i0] = baseB; eB[i1] = baseB + b0;
  eC[i0] = baseC; eC[i1] = baseC + c0;
  if (i0 < NB) { bsumA[i0] = baseA; bsumB[i0] = baseB; bsumC[i0] = baseC; }
  if (i1 < NB) { bsumA[i1] = baseA + a0; bsumB[i1] = baseB + b0; bsumC[i1] = baseC + c0; }
  __syncthreads();
  if (tid == 0) {
    int loA[TSTEPS + 1], loB[TSTEPS + 1], loC[TSTEPS + 1];
    for (int t = 0; t < TSTEPS; ++t) {
      int ib = t * N_NODES, blk = ib >> 10;
      loA[t] = scanA[ib] + eA[blk];
      loB[t] = scanB[ib] + eB[blk];
      loC[t] = scanC[ib] + eC[blk];
    }
    loA[TSTEPS] = pA[255]; loB[TSTEPS] = pB[255]; loC[TSTEPS] = pC[255];
    int f = 0;
    for (int t = 0; t < TSTEPS; ++t) {
      int cnt = loA[t + 1] - loA[t];
      meta[t] = cnt;
      meta[8 + t] = f; f |= (cnt > 0);
      meta[32 + t] = loB[t + 1] - loB[t];   // segcnt
      meta[48 + t] = loB[t];                // seg rank base
      meta[40 + t] = loC[t + 1] - loC[t];   // zcnt
      meta[56 + t] = loC[t];                // z rank base
    }
  }
}

// finalize scan; build segments + rowof (+ -1 fill) + zlist via scan ranks
__global__ void k_scan3seg(int* __restrict__ scanA, const int* __restrict__ bsumA,
                           const int* __restrict__ scanB, const int* __restrict__ bsumB,
                           const int* __restrict__ scanC, const int* __restrict__ bsumC,
                           const int* __restrict__ hist,
                           const unsigned* __restrict__ flagbits,
                           const int* __restrict__ meta, int* __restrict__ segdst,
                           int* __restrict__ segstart, int* __restrict__ seglen,
                           int* __restrict__ rowof, int* __restrict__ zlist) {
  int i = blockIdx.x * blockDim.x + threadIdx.x;
  if (i >= NBINS) return;
  int vA = scanA[i] + bsumA[i >> 10];
  scanA[i] = vA;
  int c = hist[i];
  int t = i / N_NODES;
  int tb = t * N_NODES;
  if (c > 0) {
    int sidx = scanB[i] + bsumB[i >> 10] - meta[48 + t];
    long sb = (long)tb + sidx;
    segdst[sb] = i - tb;
    segstart[sb] = vA;
    seglen[sb] = c;
    rowof[i] = sidx;
  } else {
    rowof[i] = -1;
    if ((flagbits[i >> 5] >> (i & 31)) & 1u) {
      int zr = scanC[i] + bsumC[i >> 10] - meta[56 + t];
      zlist[(long)tb + zr] = i - tb;
    }
  }
}

// setup1: place edges + embed gather + lstm(0)
__global__ __launch_bounds__(256) void k_setup1(
    const int* __restrict__ et, const int* __restrict__ src,
    const int* __restrict__ dst, const float* __restrict__ ew,
    int* __restrict__ scanA, int2* __restrict__ sedge,
    const short* __restrict__ table16, const int* __restrict__ wid,
    short* __restrict__ hb, const float* __restrict__ hxA, float* __restrict__ hxB,
    float* __restrict__ cx, const float* __restrict__ Wih,
    const float* __restrict__ Whh, const float* __restrict__ bih,
    const float* __restrict__ bhh, const int* __restrict__ meta,
    short* __restrict__ WtT) {
  __shared__ float lb[2048];
  int bid = blockIdx.x;
  int tid = threadIdx.x;
  if (bid < B_PLACE) {
    int e = bid * 256 + tid;
    if (e < E_EDGES) {
      int t = et[e];
      int bin = t * N_NODES + dst[e];
      int pos = atomicAdd(&scanA[bin], 1);
      sedge[pos] = make_int2(src[e], __float_as_int(ew[e]));
    }
  } else if (bid < B_PLACE + B_EMBED) {
    int l = tid & 31;
    for (int n = (bid - B_PLACE) * 8 + (tid >> 5); n < N_NODES; n += B_EMBED * 8) {
      *reinterpret_cast<s16x4*>(&hb[(long)n * DIM + l * 4]) =
          *reinterpret_cast<const s16x4*>(&table16[(long)wid[n] * DIM + l * 4]);
    }
  } else {
    lstm_body(bid - B_PLACE - B_EMBED, hxA, hxB, cx, Wih, Whh, bih, bhh, meta,
              WtT, 0, lb, lb + 1024);
  }
}

// loop launch A: fused scat0+gemm0 (P2b = relu(segsum(hb) @ WtT[t][0])) ∥ lstm(t+1)
__global__ __launch_bounds__(256) void k_A(
    const int* __restrict__ ss, const int* __restrict__ sl,
    const int2* __restrict__ sedge, const short* __restrict__ hb,
    const short* __restrict__ Wt0, short* __restrict__ P2b,
    const int* __restrict__ nsegp, const float* __restrict__ hxc,
    float* __restrict__ hxn, float* __restrict__ cx,
    const float* __restrict__ Wih, const float* __restrict__ Whh,
    const float* __restrict__ bih, const float* __restrict__ bhh,
    const int* __restrict__ meta, short* __restrict__ WtNext, int k) {
  __shared__ short As2[128 * 128];
  __shared__ short Ws[128 * 64];
  int bid = blockIdx.x;
  if (bid < GB) {
    fusedgemm_body<false, false>(ss, sl, sedge, hb, nullptr, Wt0, P2b, nullptr,
                                 nsegp, As2, Ws, bid);
  } else if (k < TSTEPS) {
    float* lb = (float*)As2;
    lstm_body(bid - GB, hxc, hxn, cx, Wih, Whh, bih, bhh, meta, WtNext, k,
              lb, lb + 1024);
  }
}

// loop launch B: fused scat1+gemm1 (hb[segdst] = relu(segsum(P2b) @ WtT[t][1])) ∥ zzero
__global__ __launch_bounds__(256) void k_B(
    const int* __restrict__ ss, const int* __restrict__ sl,
    const int2* __restrict__ sedge, const short* __restrict__ P2b,
    const int* __restrict__ ro, const short* __restrict__ Wt1,
    short* __restrict__ hb, const int* __restrict__ sd,
    const int* __restrict__ nsegp, const int* __restrict__ zl,
    const int* __restrict__ nzp) {
  __shared__ short As2[128 * 128];
  __shared__ short Ws[128 * 64];
  int bid = blockIdx.x;
  if (bid < GB) {
    fusedgemm_body<true, true>(ss, sl, sedge, P2b, ro, Wt1, hb, sd, nsegp,
                               As2, Ws, bid);
  } else {
    zzero_body(hb, zl, nzp, bid - GB, B_ZZ);
  }
}

// segment max (vectorized, block-reduced) + fused final via completion counter
__global__ __launch_bounds__(256) void k_segmax(
    const short* __restrict__ hb, const int* __restrict__ gid,
    unsigned* __restrict__ keys, const float* __restrict__ outW,
    const float* __restrict__ outB, const float* __restrict__ y,
    float* __restrict__ out, int* __restrict__ counter) {
  __shared__ float red[256 * 8];
  __shared__ float lt[BGRAPH];
  __shared__ int lastflag;
  int tid = threadIdx.x;
  int c = tid & 15;   // dim group: dims c*8 .. c*8+7
  int r = tid >> 4;   // row lane: rows n0+r, n0+r+16, ...
  int n0 = blockIdx.x * 128;
  int nend = min(n0 + 128, N_NODES);
  float m[8];
#pragma unroll
  for (int j = 0; j < 8; ++j) m[j] = -INFINITY;
  if (gid[n0] == gid[nend - 1]) {
    // uniform block: one graph; accumulate then LDS tree-reduce, 8 atomics/lane0
    int g = gid[n0];
#pragma unroll
    for (int it = 0; it < 8; ++it) {
      int n = n0 + it * 16 + r;
      if (n < N_NODES) {
        s16x8 v = *(const s16x8*)&hb[(long)n * DIM + c * 8];
#pragma unroll
        for (int j = 0; j < 8; ++j) m[j] = fmaxf(m[j], bf2f(v[j]));
      }
    }
#pragma unroll
    for (int j = 0; j < 8; ++j) red[tid * 8 + j] = m[j];
    __syncthreads();
    for (int off = 8; off >= 1; off >>= 1) {
      if (r < off) {
#pragma unroll
        for (int j = 0; j < 8; ++j)
          red[tid * 8 + j] = fmaxf(red[tid * 8 + j], red[(tid + off * 16) * 8 + j]);
      }
      __syncthreads();
    }
    if (r == 0) {
#pragma unroll
      for (int j = 0; j < 8; ++j)
        atomicMax(&keys[(long)g * DIM + c * 8 + j], fenc(red[tid * 8 + j]));
    }
  } else {
    // boundary block (rare): per-thread running max with flush on gid change
    int curg = -1;
#pragma unroll
    for (int it = 0; it < 8; ++it) {
      int n = n0 + it * 16 + r;
      if (n >= N_NODES) break;
      int g = gid[n];
      if (g != curg) {
        if (curg >= 0) {
#pragma unroll
          for (int j = 0; j < 8; ++j)
            atomicMax(&keys[(long)curg * DIM + c * 8 + j], fenc(m[j]));
        }
        curg = g;
#pragma unroll
        for (int j = 0; j < 8; ++j) m[j] = -INFINITY;
      }
      s16x8 v = *(const s16x8*)&hb[(long)n * DIM + c * 8];
#pragma unroll
      for (int j = 0; j < 8; ++j) m[j] = fmaxf(m[j], bf2f(v[j]));
    }
    if (curg >= 0) {
#pragma unroll
      for (int j = 0; j < 8; ++j)
        atomicMax(&keys[(long)curg * DIM + c * 8 + j], fenc(m[j]));
    }
  }
  __threadfence();
  __syncthreads();
  if (tid == 0) {
    int cc = atomicAdd(counter, 1);
    lastflag = (cc == gridDim.x - 1);
  }
  __syncthreads();
  if (lastflag) {
    __threadfence();
    if (tid < 64) {
      int b = tid >> 2, l4 = tid & 3;
      float s = 0.f;
      for (int dd = l4; dd < DIM; dd += 4) {
        unsigned kv = atomicOr(&keys[(long)b * DIM + dd], 0u);  // L2-coherent read
        float v = fdec(kv);
        if (!isfinite(v)) v = 0.f;
        s += v * outW[dd];
      }
      s += __shfl_down(s, 1);
      s += __shfl_down(s, 2);
      if (l4 == 0) {
        float l = s + outB[0];
        out[1 + b] = 1.f / (1.f + expf(-l));
        lt[b] = fmaxf(l, 0.f) - l * y[b] + log1pf(expf(-fabsf(l)));
      }
    }
    __syncthreads();
    if (tid == 0) {
      float acc = 0.f;
      for (int i = 0; i < BGRAPH; ++i) acc += lt[i];
      out[0] = acc / (float)BGRAPH;
    }
  }
}

extern "C" void kernel_launch(void* const* d_in, const int* in_sizes, int n_in,
                              void* d_out, int out_size, void* d_ws, size_t ws_size,
                              hipStream_t stream) {
  const int* word_ids = (const int*)d_in[0];
  const int* src = (const int*)d_in[1];
  const int* dst = (const int*)d_in[2];
  const int* et = (const int*)d_in[3];
  const float* ew = (const float*)d_in[4];
  const int* gid = (const int*)d_in[5];
  const float* y = (const float*)d_in[6];
  const float* wemb = (const float*)d_in[7];
  const float* adW = (const float*)d_in[8];
  const float* adb = (const float*)d_in[9];
  const float* gcn = (const float*)d_in[10];
  const float* Wih = (const float*)d_in[11];
  const float* Whh = (const float*)d_in[12];
  const float* bih = (const float*)d_in[13];
  const float* bhh = (const float*)d_in[14];
  const float* outW = (const float*)d_in[15];
  const float* outB = (const float*)d_in[16];
  float* out = (float*)d_out;

  char* ws = (char*)d_ws;
  const long ND = (long)N_NODES * DIM;
  short* hb = (short*)ws;       ws += ND * 2;
  short* P2b = (short*)ws;      ws += ND * 2;
  float* hxA = (float*)ws;      ws += LLAYERS * DIM * DIM * 4;
  float* hxB = (float*)ws;      ws += LLAYERS * DIM * DIM * 4;
  float* cx = (float*)ws;       ws += LLAYERS * DIM * DIM * 4;
  int* meta = (int*)ws;         ws += 64 * 4;
  unsigned* keys = (unsigned*)ws; ws += BGRAPH * DIM * 4;
  int* hist = (int*)ws;         ws += (long)NBINS * 4;
  int* scanA = (int*)ws;        ws += (long)NBINS * 4;
  int* scanB = (int*)ws;        ws += (long)NBINS * 4;
  int* scanC = (int*)ws;        ws += (long)NBINS * 4;
  int* bsumA = (int*)ws;        ws += ((NB + 63) & ~63) * 4;
  int* bsumB = (int*)ws;        ws += ((NB + 63) & ~63) * 4;
  int* bsumC = (int*)ws;        ws += ((NB + 63) & ~63) * 4;
  int* rowof = (int*)ws;        ws += (long)NBINS * 4;
  int* segdst = (int*)ws;       ws += (long)NBINS * 4;
  int* segstart = (int*)ws;     ws += (long)NBINS * 4;
  int* seglen = (int*)ws;       ws += (long)NBINS * 4;
  int* zlist = (int*)ws;        ws += (long)NBINS * 4;
  int2* sedge = (int2*)ws;      ws += (long)E_EDGES * 8;
  unsigned* flagbits = (unsigned*)ws; ws += ((NBINS + 31) / 32 + 64) * 4;
  short* table16 = (short*)ws;  ws += (long)NWORDS * DIM * 2;
  short* WtAd = (short*)ws;     ws += 4L * DIM * 64 * 2;
  short* WtT = (short*)ws;      ws += 7L * 2 * 16384 * 2;  // [t][layer] bf16 tiles

  // ---- setup (6 launches) ----
  k_setup0<<<B_INITP + B_PREP, 256, 0, stream>>>(gcn, hxA, cx, meta, keys, hist,
                                                 flagbits, adW, WtAd);
  k_histg<<<B_HIST + B_TGEMM, 256, 0, stream>>>(et, src, dst, hist, flagbits,
                                                wemb, WtAd, adb, table16);
  k_scan1b<<<NB, 256, 0, stream>>>(hist, flagbits, scanA, scanB, scanC,
                                   bsumA, bsumB, bsumC);
  k_scan2p<<<1, 256, 0, stream>>>(bsumA, bsumB, bsumC, scanA, scanB, scanC, meta);
  k_scan3seg<<<B_INITP, 256, 0, stream>>>(scanA, bsumA, scanB, bsumB, scanC, bsumC,
                                          hist, flagbits, meta, segdst, segstart,
                                          seglen, rowof, zlist);
  k_setup1<<<B_PLACE + B_EMBED + B_LSTM, 256, 0, stream>>>(
      et, src, dst, ew, scanA, sedge, table16, word_ids, hb, hxA, hxB, cx,
      Wih, Whh, bih, bhh, meta, WtT);

  // ---- t-loop (2 launches per step) ----
  for (int t = 0; t < TSTEPS; ++t) {
    const int* nsegp = &meta[32 + t];
    const int* nzp = &meta[40 + t];
    const int* ss = segstart + (long)t * N_NODES;
    const int* sl = seglen + (long)t * N_NODES;
    const int* sd = segdst + (long)t * N_NODES;
    const int* ro = rowof + (long)t * N_NODES;
    const int* zl = zlist + (long)t * N_NODES;
    int k = t + 1;  // prefetched lstm step
    const float* hxc = (k & 1) ? hxB : hxA;
    float* hxn = (k & 1) ? hxA : hxB;
    k_A<<<GB + B_LSTM, 256, 0, stream>>>(
        ss, sl, sedge, hb, WtT + (long)t * 2 * 16384, P2b, nsegp,
        hxc, hxn, cx, Wih, Whh, bih, bhh, meta, WtT + (long)k * 2 * 16384, k);
    k_B<<<GB + B_ZZ, 256, 0, stream>>>(
        ss, sl, sedge, P2b, ro, WtT + ((long)t * 2 + 1) * 16384, hb, sd, nsegp,
        zl, nzp);
  }

  k_segmax<<<B_SEGMAX, 256, 0, stream>>>(hb, gid, keys, outW, outB, y, out,
                                         &meta[62]);
}

// Round 11
// 324.416 us; speedup vs baseline: 1.2441x; 1.1505x over previous
//
#include <hip/hip_runtime.h>
#include <hip/hip_bf16.h>
#include <math.h>

#define N_NODES 60000
#define E_EDGES 200000
#define DIM     128
#define NINPK   256
#define TSTEPS  6
#define LLAYERS 2
#define BGRAPH  16
#define NBINS   (TSTEPS * N_NODES)          // 360000
#define NB      ((NBINS + 1023) / 1024)     // 352 scan blocks
#define NWORDS  15000

#define B_INITP  ((NBINS + 255) / 256)          // 1407
#define B_PREP   16
#define B_HIST   ((E_EDGES + 255) / 256)        // 782
#define B_TGEMM  ((NWORDS + 127) / 128)         // 118
#define B_PLACE5 ((E_EDGES + 511) / 512)        // 391 (512-thr)
#define B_EMBED  512
#define B_LSTM5  64                             // 4 cols/block @512 thr
#define GB       ((N_NODES + 127) / 128)        // 469 (dyn early-exit on nseg)
#define B_ZZ     64
#define B_SEGMAX ((N_NODES + 127) / 128)        // 469

typedef float f32x4 __attribute__((ext_vector_type(4)));
typedef short s16x8 __attribute__((ext_vector_type(8)));
typedef short s16x4 __attribute__((ext_vector_type(4)));

static __device__ __forceinline__ float sigm(float x) { return 1.f / (1.f + expf(-x)); }

static __device__ __forceinline__ short f2bf(float f) {
  unsigned u = __float_as_uint(f);
  u += 0x7FFFu + ((u >> 16) & 1u);
  return (short)(u >> 16);
}
static __device__ __forceinline__ float bf2f(short s) {
  return __uint_as_float(((unsigned)(unsigned short)s) << 16);
}
static __device__ __forceinline__ unsigned fenc(float f) {
  unsigned u = __float_as_uint(f);
  return (u & 0x80000000u) ? ~u : (u | 0x80000000u);
}
static __device__ __forceinline__ float fdec(unsigned u) {
  u = (u & 0x80000000u) ? (u & 0x7fffffffu) : ~u;
  return __uint_as_float(u);
}

// ============ device bodies ============

// ---- 256-thread GEMM compute+epi (used by table GEMM only) ----
template <bool RELU, bool BIAS, bool GOUT>
static __device__ __forceinline__ void gemm_compute_epi256(
    f32x4 (&acc)[2][8], const short* WtKt, const float* bias, short* C16,
    const int* dstmap, int N, int n0, const short* As, int rsg, int ktg,
    short* Ws, bool last) {
  const int tid = threadIdx.x;
  const int lane = tid & 63;
  const int w = tid >> 6;
  __syncthreads();
  const int4* wg = reinterpret_cast<const int4*>(WtKt);
  int4* wl = reinterpret_cast<int4*>(Ws);
#pragma unroll
  for (int p = 0; p < 4; ++p) wl[p * 256 + tid] = wg[p * 256 + tid];
  __syncthreads();
#pragma unroll
  for (int kk = 0; kk < 2; ++kk) {
    int gb = kk * 4 + (lane >> 4);
    s16x8 a[2];
#pragma unroll
    for (int fr = 0; fr < 2; ++fr) {
      int row = w * 32 + fr * 16 + (lane & 15);
      a[fr] = *(const s16x8*)&As[(row * rsg + ktg + (gb ^ (row & 7))) * 8];
    }
#pragma unroll
    for (int fc = 0; fc < 8; ++fc) {
      int col = fc * 16 + (lane & 15);
      s16x8 b = *(const s16x8*)&Ws[(col * 8 + (gb ^ (col & 7))) * 8];
      acc[0][fc] = __builtin_amdgcn_mfma_f32_16x16x32_bf16(a[0], b, acc[0][fc], 0, 0, 0);
      acc[1][fc] = __builtin_amdgcn_mfma_f32_16x16x32_bf16(a[1], b, acc[1][fc], 0, 0, 0);
    }
  }
  if (!last) return;
  const int cb = lane & 15;
  const int rb = w * 32 + (lane >> 4) * 4;
#pragma unroll
  for (int fr = 0; fr < 2; ++fr) {
#pragma unroll
    for (int reg = 0; reg < 4; ++reg) {
      int n = n0 + rb + fr * 16 + reg;
      if (n >= N) continue;
      long drow = GOUT ? (long)dstmap[n] : (long)n;
      short* cp = C16 + drow * DIM;
#pragma unroll
      for (int fc = 0; fc < 8; ++fc) {
        float x = acc[fr][fc][reg];
        if (BIAS) x += bias[fc * 16 + cb];
        if (RELU) x = fmaxf(x, 0.f);
        cp[fc * 16 + cb] = f2bf(x);
      }
    }
  }
}

// ---- 512-thread fused segscatter+GEMM ----
// phase 0: 32 groups x 16 lanes scatter segment-sums into As2[128][128]
// (4 serial its/thread instead of 8 -> halved gather-latency chain);
// phase 1: 8 waves x 16-row fragments, 2 k-tile MFMA passes.
template <bool PACKEDIN, bool GOUT>
static __device__ __forceinline__ void fusedgemm512(
    const int* __restrict__ ss, const int* __restrict__ sl,
    const int2* __restrict__ sedge, const short* __restrict__ IN16,
    const int* __restrict__ ro, const short* __restrict__ Wt,
    short* __restrict__ C16, const int* __restrict__ sd,
    const int* __restrict__ nsegp, short* As2, short* Ws, int bid) {
  const int N = nsegp[0];
  const int n0 = bid * 128;
  if (n0 >= N) return;
  const int tid = threadIdx.x;        // 0..511
  const int lane16 = tid & 15;
  const int grp = tid >> 4;           // 0..31
#pragma unroll
  for (int it = 0; it < 4; ++it) {
    int row = it * 32 + grp;
    int seg = n0 + row;
    float a0 = 0, a1 = 0, a2 = 0, a3 = 0, a4 = 0, a5 = 0, a6 = 0, a7 = 0;
    if (seg < N) {
      int st = ss[seg], en = st + sl[seg];
      for (int e = st; e < en; ++e) {
        int2 v = sedge[e];
        int r2 = PACKEDIN ? ro[v.x] : v.x;
        if (PACKEDIN && r2 < 0) continue;
        float w = __int_as_float(v.y);
        s16x8 hv = *(const s16x8*)&IN16[(long)r2 * DIM + lane16 * 8];
        a0 = fmaf(w, bf2f(hv[0]), a0); a1 = fmaf(w, bf2f(hv[1]), a1);
        a2 = fmaf(w, bf2f(hv[2]), a2); a3 = fmaf(w, bf2f(hv[3]), a3);
        a4 = fmaf(w, bf2f(hv[4]), a4); a5 = fmaf(w, bf2f(hv[5]), a5);
        a6 = fmaf(w, bf2f(hv[6]), a6); a7 = fmaf(w, bf2f(hv[7]), a7);
      }
    }
    s16x8 outv;
    outv[0] = f2bf(a0); outv[1] = f2bf(a1); outv[2] = f2bf(a2); outv[3] = f2bf(a3);
    outv[4] = f2bf(a4); outv[5] = f2bf(a5); outv[6] = f2bf(a6); outv[7] = f2bf(a7);
    int slot = (lane16 & 8) | ((lane16 & 7) ^ (row & 7));
    *(s16x8*)&As2[(row * 16 + slot) * 8] = outv;
  }
  const int lane = tid & 63;
  const int w = tid >> 6;             // 0..7 waves
  f32x4 acc[8] = {};
#pragma unroll
  for (int kt = 0; kt < 2; ++kt) {
    __syncthreads();                  // As2 ready / prior Ws reads done
    const int4* wg = reinterpret_cast<const int4*>(Wt + kt * 128 * 64);
    int4* wl = reinterpret_cast<int4*>(Ws);
#pragma unroll
    for (int p = 0; p < 2; ++p) wl[p * 512 + tid] = wg[p * 512 + tid];
    __syncthreads();
#pragma unroll
    for (int kk = 0; kk < 2; ++kk) {
      int gb = kk * 4 + (lane >> 4);
      int row = w * 16 + (lane & 15);
      s16x8 a = *(const s16x8*)&As2[(row * 16 + kt * 8 + (gb ^ (row & 7))) * 8];
#pragma unroll
      for (int fc = 0; fc < 8; ++fc) {
        int col = fc * 16 + (lane & 15);
        s16x8 b = *(const s16x8*)&Ws[(col * 8 + (gb ^ (col & 7))) * 8];
        acc[fc] = __builtin_amdgcn_mfma_f32_16x16x32_bf16(a, b, acc[fc], 0, 0, 0);
      }
    }
  }
  // epilogue: C/D layout col=lane&15, row=(lane>>4)*4+reg  [m89-verified]
  const int cb = lane & 15;
  const int rb = w * 16 + (lane >> 4) * 4;
#pragma unroll
  for (int reg = 0; reg < 4; ++reg) {
    int n = n0 + rb + reg;
    if (n >= N) continue;
    long drow = GOUT ? (long)sd[n] : (long)n;
    short* cp = C16 + drow * DIM;
#pragma unroll
    for (int fc = 0; fc < 8; ++fc) {
      float x = fmaxf(acc[fc][reg], 0.f);
      cp[fc * 16 + cb] = f2bf(x);
    }
  }
}

// table GEMM (256 thr): table16[w] = wemb[w] @ WtAd + adb
static __device__ __forceinline__ void tablegemm_body(
    const float* __restrict__ Af, const short* __restrict__ Wt,
    const float* __restrict__ bias, short* __restrict__ table16, short* As,
    short* Ws, int bid) {
  const int n0 = bid * 128;
  const int tid = threadIdx.x;
  f32x4 acc[2][8] = {};
#pragma unroll
  for (int kt = 0; kt < 4; ++kt) {
    __syncthreads();
#pragma unroll
    for (int p = 0; p < 4; ++p) {
      int gi = p * 256 + tid;
      int row = gi >> 3, s = gi & 7;
      int n = n0 + row;
      s16x8 v = {};
      if (n < NWORDS) {
        const float* ap = Af + (long)n * NINPK + kt * 64 + (s ^ (row & 7)) * 8;
        float4 v0 = *reinterpret_cast<const float4*>(ap);
        float4 v1 = *reinterpret_cast<const float4*>(ap + 4);
        v[0] = f2bf(v0.x); v[1] = f2bf(v0.y); v[2] = f2bf(v0.z); v[3] = f2bf(v0.w);
        v[4] = f2bf(v1.x); v[5] = f2bf(v1.y); v[6] = f2bf(v1.z); v[7] = f2bf(v1.w);
      }
      *(s16x8*)&As[(row * 8 + s) * 8] = v;
    }
    gemm_compute_epi256<false, true, false>(acc, Wt + kt * 128 * 64, bias, table16,
                                            nullptr, NWORDS, n0, As, 8, 0, Ws,
                                            kt == 3);
  }
}

// zero src-only touched hb rows (512 thr)
static __device__ __forceinline__ void zzero_body(short* __restrict__ hb,
                                                  const int* __restrict__ zl,
                                                  const int* __restrict__ nzp,
                                                  int bid, int nblocks) {
  int nz = nzp[0];
  int l = threadIdx.x & 31;
  s16x4 z = {};
  for (int s = bid * 16 + (threadIdx.x >> 5); s < nz; s += nblocks * 16) {
    *reinterpret_cast<s16x4*>(&hb[(long)zl[s] * DIM + l * 4]) = z;
  }
}

// fused LSTM step k (512 thr, 4 cols/block): gates, select, hx/cx update,
// writes bf16 weight tiles WtBase + layer*16384
static __device__ __forceinline__ void lstm_body512(
    int bid, const float* __restrict__ hxc, float* __restrict__ hxn,
    float* __restrict__ cx, const float* __restrict__ Wih,
    const float* __restrict__ Whh, const float* __restrict__ bih,
    const float* __restrict__ bhh, const int* __restrict__ meta,
    short* __restrict__ WtBase, int k, float* wi, float* wh) {
  int tid = threadIdx.x;               // 0..511
  int i = bid >> 5;                    // layer (64 blocks: 32/layer)
  int j4 = bid & 31;
  int jl = tid >> 7;                   // 0..3
  int r = tid & 127;
  int j = j4 * 4 + jl;
  float* wiL = wi + jl * 512;
  float* whL = wh + jl * 512;
#pragma unroll
  for (int g4 = 0; g4 < 4; ++g4) {
    wiL[g4 * 128 + r] = Wih[((long)i * 512 + g4 * 128 + j) * DIM + r];
    whL[g4 * 128 + r] = Whh[((long)i * 512 + g4 * 128 + j) * DIM + r];
  }
  __syncthreads();
  const float4* x4 = reinterpret_cast<const float4*>(hxc + ((long)i * DIM + r) * DIM);
  float a0 = 0, a1 = 0, a2 = 0, a3 = 0, b0 = 0, b1 = 0, b2 = 0, b3 = 0;
#pragma unroll 4
  for (int k4 = 0; k4 < 32; ++k4) {
    float4 xv = x4[k4];
    const float* vp = &xv.x;
#pragma unroll
    for (int q = 0; q < 4; ++q) {
      int kk = k4 * 4 + q;
      float xs = vp[q];
      a0 = fmaf(xs, wiL[kk], a0);       a1 = fmaf(xs, wiL[128 + kk], a1);
      a2 = fmaf(xs, wiL[256 + kk], a2); a3 = fmaf(xs, wiL[384 + kk], a3);
      b0 = fmaf(xs, whL[kk], b0);       b1 = fmaf(xs, whL[128 + kk], b1);
      b2 = fmaf(xs, whL[256 + kk], b2); b3 = fmaf(xs, whL[384 + kk], b3);
    }
  }
  int cbi = i * 512 + j;
  float g0i = a0 + bih[cbi] + bhh[cbi];
  float g0f = a1 + bih[cbi + 128] + bhh[cbi + 128];
  float g0g = a2 + bih[cbi + 256] + bhh[cbi + 256];
  float g0o = a3 + bih[cbi + 384] + bhh[cbi + 384];
  float g1i = g0i + b0, g1f = g0f + b1, g1g = g0g + b2, g1o = g0o + b3;
  int idx = i * 16384 + r * 128 + j;
  float c0v = cx[idx];
  float c_zero = sigm(g0i) * tanhf(g0g);
  float h_zero = sigm(g0o) * tanhf(c_zero);
  float c_st = sigm(g1f) * c0v + sigm(g1i) * tanhf(g1g);
  float h_st = sigm(g1o) * tanhf(c_st);
  int first = meta[8 + k];
  int has = meta[k] > 0;
  float hi_v = first ? h_st : h_zero;
  float ci_v = first ? c0v : c_zero;
  float xj = reinterpret_cast<const float*>(x4)[j];
  float hnew = has ? hi_v : xj;
  float cnew = has ? ci_v : c0v;
  hxn[idx] = hnew;
  cx[idx] = cnew;
  short* Wt = WtBase + i * 16384;
  int kb = r >> 6, g = (r >> 3) & 7, jj = r & 7;
  Wt[((kb * DIM + j) * 8 + (g ^ (j & 7))) * 8 + jj] = f2bf(hnew);
}

// ============ kernels ============

// setup0: init state/hist/flags/meta/keys + adaptW bf16 tiles
__global__ void k_setup0(const float* __restrict__ gcn, float* __restrict__ hxA,
                         float* __restrict__ cx, int* __restrict__ meta,
                         unsigned* __restrict__ keys, int* __restrict__ hist,
                         unsigned* __restrict__ flagbits,
                         const float* __restrict__ adW, short* __restrict__ WtAd) {
  int bid = blockIdx.x;
  int tid = threadIdx.x;
  if (bid < B_INITP) {
    int i = bid * 256 + tid;
    if (i < LLAYERS * DIM * DIM) { hxA[i] = gcn[i]; cx[i] = 0.f; }
    if (i < BGRAPH * DIM) keys[i] = 0u;
    if (i < 64) meta[i] = 0;
    if (i < NBINS) hist[i] = 0;
    if (i < (NBINS + 31) / 32) flagbits[i] = 0u;
  } else {
    int idx = (bid - B_INITP) * 256 + tid;  // < 4096
    int g = idx & 7;
    int c = (idx >> 3) & 127;
    int kb = idx >> 10;
    s16x8 s;
#pragma unroll
    for (int j = 0; j < 8; ++j) s[j] = f2bf(adW[(long)(kb * 64 + g * 8 + j) * DIM + c]);
    *(s16x8*)&WtAd[(((long)kb * DIM + c) * 8 + (g ^ (c & 7))) * 8] = s;
  }
}

// hist/flag atomics + table GEMM (fp32 wemb direct), 256 thr
__global__ __launch_bounds__(256) void k_histg(
    const int* __restrict__ et, const int* __restrict__ src,
    const int* __restrict__ dst, int* __restrict__ hist,
    unsigned* __restrict__ flagbits, const float* __restrict__ wemb,
    const short* __restrict__ WtAd, const float* __restrict__ adb,
    short* __restrict__ table16) {
  __shared__ short As[128 * 64];
  __shared__ short Ws[128 * 64];
  int bid = blockIdx.x;
  if (bid < B_HIST) {
    int e = bid * 256 + threadIdx.x;
    if (e < E_EDGES) {
      int t = et[e];
      atomicAdd(&hist[t * N_NODES + dst[e]], 1);
      int fs = t * N_NODES + src[e];
      atomicOr(&flagbits[fs >> 5], 1u << (fs & 31));
    }
  } else {
    tablegemm_body(wemb, WtAd, adb, table16, As, Ws, bid - B_HIST);
  }
}

// fused 2-level exclusive scan: hist values, nonempty indicator, z indicator
__global__ void k_scan1b(const int* __restrict__ hist,
                         const unsigned* __restrict__ flagbits,
                         int* __restrict__ scanA, int* __restrict__ scanB,
                         int* __restrict__ scanC, int* __restrict__ bsumA,
                         int* __restrict__ bsumB, int* __restrict__ bsumC) {
  __shared__ int shA[256], shB[256], shC[256];
  int b0 = blockIdx.x * 1024;
  int tid = threadIdx.x;
  int v[4], w[4], z[4];
  int sA = 0, sB = 0, sC = 0;
#pragma unroll
  for (int q = 0; q < 4; ++q) {
    int i = b0 + tid * 4 + q;
    int c = (i < NBINS) ? hist[i] : 0;
    int fl = (i < NBINS) ? (int)((flagbits[i >> 5] >> (i & 31)) & 1u) : 0;
    v[q] = c; w[q] = (c > 0) ? 1 : 0; z[q] = (fl && c == 0) ? 1 : 0;
    sA += c; sB += w[q]; sC += z[q];
  }
  shA[tid] = sA; shB[tid] = sB; shC[tid] = sC;
  __syncthreads();
  for (int off = 1; off < 256; off <<= 1) {
    int xA = (tid >= off) ? shA[tid - off] : 0;
    int xB = (tid >= off) ? shB[tid - off] : 0;
    int xC = (tid >= off) ? shC[tid - off] : 0;
    __syncthreads();
    shA[tid] += xA; shB[tid] += xB; shC[tid] += xC;
    __syncthreads();
  }
  int exA = shA[tid] - sA, exB = shB[tid] - sB, exC = shC[tid] - sC;
#pragma unroll
  for (int q = 0; q < 4; ++q) {
    int i = b0 + tid * 4 + q;
    if (i < NBINS) { scanA[i] = exA; scanB[i] = exB; scanC[i] = exC; }
    exA += v[q]; exB += w[q]; exC += z[q];
  }
  if (tid == 255) {
    bsumA[blockIdx.x] = shA[255];
    bsumB[blockIdx.x] = shB[255];
    bsumC[blockIdx.x] = shC[255];
  }
}

// parallel block-sum scan (3 channels) + all meta fields
__global__ __launch_bounds__(256) void k_scan2p(
    int* __restrict__ bsumA, int* __restrict__ bsumB, int* __restrict__ bsumC,
    const int* __restrict__ scanA, const int* __restrict__ scanB,
    const int* __restrict__ scanC, int* __restrict__ meta) {
  __shared__ int pA[256], pB[256], pC[256];
  __shared__ int eA[512], eB[512], eC[512];
  int tid = threadIdx.x;
  int i0 = tid * 2, i1 = tid * 2 + 1;
  int a0 = (i0 < NB) ? bsumA[i0] : 0, a1 = (i1 < NB) ? bsumA[i1] : 0;
  int b0 = (i0 < NB) ? bsumB[i0] : 0, b1 = (i1 < NB) ? bsumB[i1] : 0;
  int c0 = (i0 < NB) ? bsumC[i0] : 0, c1 = (i1 < NB) ? bsumC[i1] : 0;
  int tA = a0 + a1, tB = b0 + b1, tC = c0 + c1;
  pA[tid] = tA; pB[tid] = tB; pC[tid] = tC;
  __syncthreads();
  for (int off = 1; off < 256; off <<= 1) {
    int xA = (tid >= off) ? pA[tid - off] : 0;
    int xB = (tid >= off) ? pB[tid - off] : 0;
    int xC = (tid >= off) ? pC[tid - off] : 0;
    __syncthreads();
    pA[tid] += xA; pB[tid] += xB; pC[tid] += xC;
    __syncthreads();
  }
  int baseA = pA[tid] - tA, baseB = pB[tid] - tB, baseC = pC[tid] - tC;
  eA[i0] = baseA; eA[i1] = baseA + a0;
  eB[i0] = baseB; eB[i1] = baseB + b0;
  eC[i0] = baseC; eC[i1] = baseC + c0;
  if (i0 < NB) { bsumA[i0] = baseA; bsumB[i0] = baseB; bsumC[i0] = baseC; }
  if (i1 < NB) { bsumA[i1] = baseA + a0; bsumB[i1] = baseB + b0; bsumC[i1] = baseC + c0; }
  __syncthreads();
  if (tid == 0) {
    int loA[TSTEPS + 1], loB[TSTEPS + 1], loC[TSTEPS + 1];
    for (int t = 0; t < TSTEPS; ++t) {
      int ib = t * N_NODES, blk = ib >> 10;
      loA[t] = scanA[ib] + eA[blk];
      loB[t] = scanB[ib] + eB[blk];
      loC[t] = scanC[ib] + eC[blk];
    }
    loA[TSTEPS] = pA[255]; loB[TSTEPS] = pB[255]; loC[TSTEPS] = pC[255];
    int f = 0;
    for (int t = 0; t < TSTEPS; ++t) {
      int cnt = loA[t + 1] - loA[t];
      meta[t] = cnt;
      meta[8 + t] = f; f |= (cnt > 0);
      meta[32 + t] = loB[t + 1] - loB[t];   // segcnt
      meta[48 + t] = loB[t];                // seg rank base
      meta[40 + t] = loC[t + 1] - loC[t];   // zcnt
      meta[56 + t] = loC[t];                // z rank base
    }
  }
}

// finalize scan; build segments + rowof (+ -1 fill) + zlist via scan ranks
__global__ void k_scan3seg(int* __restrict__ scanA, const int* __restrict__ bsumA,
                           const int* __restrict__ scanB, const int* __restrict__ bsumB,
                           const int* __restrict__ scanC, const int* __restrict__ bsumC,
                           const int* __restrict__ hist,
                           const unsigned* __restrict__ flagbits,
                           const int* __restrict__ meta, int* __restrict__ segdst,
                           int* __restrict__ segstart, int* __restrict__ seglen,
                           int* __restrict__ rowof, int* __restrict__ zlist) {
  int i = blockIdx.x * blockDim.x + threadIdx.x;
  if (i >= NBINS) return;
  int vA = scanA[i] + bsumA[i >> 10];
  scanA[i] = vA;
  int c = hist[i];
  int t = i / N_NODES;
  int tb = t * N_NODES;
  if (c > 0) {
    int sidx = scanB[i] + bsumB[i >> 10] - meta[48 + t];
    long sb = (long)tb + sidx;
    segdst[sb] = i - tb;
    segstart[sb] = vA;
    seglen[sb] = c;
    rowof[i] = sidx;
  } else {
    rowof[i] = -1;
    if ((flagbits[i >> 5] >> (i & 31)) & 1u) {
      int zr = scanC[i] + bsumC[i >> 10] - meta[56 + t];
      zlist[(long)tb + zr] = i - tb;
    }
  }
}

// setup1 (512 thr): place edges + embed gather + lstm(0)
__global__ __launch_bounds__(512) void k_setup1(
    const int* __restrict__ et, const int* __restrict__ src,
    const int* __restrict__ dst, const float* __restrict__ ew,
    int* __restrict__ scanA, int2* __restrict__ sedge,
    const short* __restrict__ table16, const int* __restrict__ wid,
    short* __restrict__ hb, const float* __restrict__ hxA, float* __restrict__ hxB,
    float* __restrict__ cx, const float* __restrict__ Wih,
    const float* __restrict__ Whh, const float* __restrict__ bih,
    const float* __restrict__ bhh, const int* __restrict__ meta,
    short* __restrict__ WtT) {
  __shared__ float lb[4096];
  int bid = blockIdx.x;
  int tid = threadIdx.x;
  if (bid < B_PLACE5) {
    int e = bid * 512 + tid;
    if (e < E_EDGES) {
      int t = et[e];
      int bin = t * N_NODES + dst[e];
      int pos = atomicAdd(&scanA[bin], 1);
      sedge[pos] = make_int2(src[e], __float_as_int(ew[e]));
    }
  } else if (bid < B_PLACE5 + B_EMBED) {
    int l = tid & 31;
    for (int n = (bid - B_PLACE5) * 16 + (tid >> 5); n < N_NODES; n += B_EMBED * 16) {
      *reinterpret_cast<s16x4*>(&hb[(long)n * DIM + l * 4]) =
          *reinterpret_cast<const s16x4*>(&table16[(long)wid[n] * DIM + l * 4]);
    }
  } else {
    lstm_body512(bid - B_PLACE5 - B_EMBED, hxA, hxB, cx, Wih, Whh, bih, bhh, meta,
                 WtT, 0, lb, lb + 2048);
  }
}

// loop launch A (512 thr): fused scat0+gemm0 ∥ lstm(t+1)
__global__ __launch_bounds__(512) void k_A(
    const int* __restrict__ ss, const int* __restrict__ sl,
    const int2* __restrict__ sedge, const short* __restrict__ hb,
    const short* __restrict__ Wt0, short* __restrict__ P2b,
    const int* __restrict__ nsegp, const float* __restrict__ hxc,
    float* __restrict__ hxn, float* __restrict__ cx,
    const float* __restrict__ Wih, const float* __restrict__ Whh,
    const float* __restrict__ bih, const float* __restrict__ bhh,
    const int* __restrict__ meta, short* __restrict__ WtNext, int k) {
  __shared__ short As2[128 * 128];
  __shared__ short Ws[128 * 64];
  int bid = blockIdx.x;
  if (bid < GB) {
    fusedgemm512<false, false>(ss, sl, sedge, hb, nullptr, Wt0, P2b, nullptr,
                               nsegp, As2, Ws, bid);
  } else if (k < TSTEPS) {
    float* lb = (float*)As2;
    lstm_body512(bid - GB, hxc, hxn, cx, Wih, Whh, bih, bhh, meta, WtNext, k,
                 lb, lb + 2048);
  }
}

// loop launch B (512 thr): fused scat1+gemm1 ∥ zzero
__global__ __launch_bounds__(512) void k_B(
    const int* __restrict__ ss, const int* __restrict__ sl,
    const int2* __restrict__ sedge, const short* __restrict__ P2b,
    const int* __restrict__ ro, const short* __restrict__ Wt1,
    short* __restrict__ hb, const int* __restrict__ sd,
    const int* __restrict__ nsegp, const int* __restrict__ zl,
    const int* __restrict__ nzp) {
  __shared__ short As2[128 * 128];
  __shared__ short Ws[128 * 64];
  int bid = blockIdx.x;
  if (bid < GB) {
    fusedgemm512<true, true>(ss, sl, sedge, P2b, ro, Wt1, hb, sd, nsegp,
                             As2, Ws, bid);
  } else {
    zzero_body(hb, zl, nzp, bid - GB, B_ZZ);
  }
}

// segment max: vectorized 16B loads, LDS tree reduce, atomicMax only.
// NO device fences — cross-kernel visibility via dispatch boundary.
__global__ __launch_bounds__(256) void k_segmax(
    const short* __restrict__ hb, const int* __restrict__ gid,
    unsigned* __restrict__ keys) {
  __shared__ float red[256 * 8];
  int tid = threadIdx.x;
  int c = tid & 15;   // dim group: dims c*8 .. c*8+7
  int r = tid >> 4;   // row lane
  int n0 = blockIdx.x * 128;
  int nend = min(n0 + 128, N_NODES);
  float m[8];
#pragma unroll
  for (int j = 0; j < 8; ++j) m[j] = -INFINITY;
  if (gid[n0] == gid[nend - 1]) {
    int g = gid[n0];
#pragma unroll
    for (int it = 0; it < 8; ++it) {
      int n = n0 + it * 16 + r;
      if (n < N_NODES) {
        s16x8 v = *(const s16x8*)&hb[(long)n * DIM + c * 8];
#pragma unroll
        for (int j = 0; j < 8; ++j) m[j] = fmaxf(m[j], bf2f(v[j]));
      }
    }
#pragma unroll
    for (int j = 0; j < 8; ++j) red[tid * 8 + j] = m[j];
    __syncthreads();
    for (int off = 8; off >= 1; off >>= 1) {
      if (r < off) {
#pragma unroll
        for (int j = 0; j < 8; ++j)
          red[tid * 8 + j] = fmaxf(red[tid * 8 + j], red[(tid + off * 16) * 8 + j]);
      }
      __syncthreads();
    }
    if (r == 0) {
#pragma unroll
      for (int j = 0; j < 8; ++j)
        atomicMax(&keys[(long)g * DIM + c * 8 + j], fenc(red[tid * 8 + j]));
    }
  } else {
    int curg = -1;
#pragma unroll
    for (int it = 0; it < 8; ++it) {
      int n = n0 + it * 16 + r;
      if (n >= N_NODES) break;
      int g = gid[n];
      if (g != curg) {
        if (curg >= 0) {
#pragma unroll
          for (int j = 0; j < 8; ++j)
            atomicMax(&keys[(long)curg * DIM + c * 8 + j], fenc(m[j]));
        }
        curg = g;
#pragma unroll
        for (int j = 0; j < 8; ++j) m[j] = -INFINITY;
      }
      s16x8 v = *(const s16x8*)&hb[(long)n * DIM + c * 8];
#pragma unroll
      for (int j = 0; j < 8; ++j) m[j] = fmaxf(m[j], bf2f(v[j]));
    }
    if (curg >= 0) {
#pragma unroll
      for (int j = 0; j < 8; ++j)
        atomicMax(&keys[(long)curg * DIM + c * 8 + j], fenc(m[j]));
    }
  }
}

// final: logits, probs, BCE loss (separate dispatch: keys visible at boundary)
__global__ void k_final(const unsigned* __restrict__ keys, const float* __restrict__ outW,
                        const float* __restrict__ outB, const float* __restrict__ y,
                        float* __restrict__ out) {
  __shared__ float lt[BGRAPH];
  int tid = threadIdx.x;
  int b = tid >> 2, l4 = tid & 3;
  float s = 0.f;
  for (int d = l4; d < DIM; d += 4) {
    float v = fdec(keys[(long)b * DIM + d]);
    if (!isfinite(v)) v = 0.f;
    s += v * outW[d];
  }
  s += __shfl_down(s, 1);
  s += __shfl_down(s, 2);
  if (l4 == 0) {
    float l = s + outB[0];
    out[1 + b] = 1.f / (1.f + expf(-l));
    lt[b] = fmaxf(l, 0.f) - l * y[b] + log1pf(expf(-fabsf(l)));
  }
  __syncthreads();
  if (tid == 0) {
    float acc = 0.f;
    for (int i = 0; i < BGRAPH; ++i) acc += lt[i];
    out[0] = acc / (float)BGRAPH;
  }
}

extern "C" void kernel_launch(void* const* d_in, const int* in_sizes, int n_in,
                              void* d_out, int out_size, void* d_ws, size_t ws_size,
                              hipStream_t stream) {
  const int* word_ids = (const int*)d_in[0];
  const int* src = (const int*)d_in[1];
  const int* dst = (const int*)d_in[2];
  const int* et = (const int*)d_in[3];
  const float* ew = (const float*)d_in[4];
  const int* gid = (const int*)d_in[5];
  const float* y = (const float*)d_in[6];
  const float* wemb = (const float*)d_in[7];
  const float* adW = (const float*)d_in[8];
  const float* adb = (const float*)d_in[9];
  const float* gcn = (const float*)d_in[10];
  const float* Wih = (const float*)d_in[11];
  const float* Whh = (const float*)d_in[12];
  const float* bih = (const float*)d_in[13];
  const float* bhh = (const float*)d_in[14];
  const float* outW = (const float*)d_in[15];
  const float* outB = (const float*)d_in[16];
  float* out = (float*)d_out;

  char* ws = (char*)d_ws;
  const long ND = (long)N_NODES * DIM;
  short* hb = (short*)ws;       ws += ND * 2;
  short* P2b = (short*)ws;      ws += ND * 2;
  float* hxA = (float*)ws;      ws += LLAYERS * DIM * DIM * 4;
  float* hxB = (float*)ws;      ws += LLAYERS * DIM * DIM * 4;
  float* cx = (float*)ws;       ws += LLAYERS * DIM * DIM * 4;
  int* meta = (int*)ws;         ws += 64 * 4;
  unsigned* keys = (unsigned*)ws; ws += BGRAPH * DIM * 4;
  int* hist = (int*)ws;         ws += (long)NBINS * 4;
  int* scanA = (int*)ws;        ws += (long)NBINS * 4;
  int* scanB = (int*)ws;        ws += (long)NBINS * 4;
  int* scanC = (int*)ws;        ws += (long)NBINS * 4;
  int* bsumA = (int*)ws;        ws += ((NB + 63) & ~63) * 4;
  int* bsumB = (int*)ws;        ws += ((NB + 63) & ~63) * 4;
  int* bsumC = (int*)ws;        ws += ((NB + 63) & ~63) * 4;
  int* rowof = (int*)ws;        ws += (long)NBINS * 4;
  int* segdst = (int*)ws;       ws += (long)NBINS * 4;
  int* segstart = (int*)ws;     ws += (long)NBINS * 4;
  int* seglen = (int*)ws;       ws += (long)NBINS * 4;
  int* zlist = (int*)ws;        ws += (long)NBINS * 4;
  int2* sedge = (int2*)ws;      ws += (long)E_EDGES * 8;
  unsigned* flagbits = (unsigned*)ws; ws += ((NBINS + 31) / 32 + 64) * 4;
  short* table16 = (short*)ws;  ws += (long)NWORDS * DIM * 2;
  short* WtAd = (short*)ws;     ws += 4L * DIM * 64 * 2;
  short* WtT = (short*)ws;      ws += 7L * 2 * 16384 * 2;  // [t][layer] bf16 tiles

  // ---- setup (6 launches) ----
  k_setup0<<<B_INITP + B_PREP, 256, 0, stream>>>(gcn, hxA, cx, meta, keys, hist,
                                                 flagbits, adW, WtAd);
  k_histg<<<B_HIST + B_TGEMM, 256, 0, stream>>>(et, src, dst, hist, flagbits,
                                                wemb, WtAd, adb, table16);
  k_scan1b<<<NB, 256, 0, stream>>>(hist, flagbits, scanA, scanB, scanC,
                                   bsumA, bsumB, bsumC);
  k_scan2p<<<1, 256, 0, stream>>>(bsumA, bsumB, bsumC, scanA, scanB, scanC, meta);
  k_scan3seg<<<B_INITP, 256, 0, stream>>>(scanA, bsumA, scanB, bsumB, scanC, bsumC,
                                          hist, flagbits, meta, segdst, segstart,
                                          seglen, rowof, zlist);
  k_setup1<<<B_PLACE5 + B_EMBED + B_LSTM5, 512, 0, stream>>>(
      et, src, dst, ew, scanA, sedge, table16, word_ids, hb, hxA, hxB, cx,
      Wih, Whh, bih, bhh, meta, WtT);

  // ---- t-loop (2 launches per step) ----
  for (int t = 0; t < TSTEPS; ++t) {
    const int* nsegp = &meta[32 + t];
    const int* nzp = &meta[40 + t];
    const int* ss = segstart + (long)t * N_NODES;
    const int* sl = seglen + (long)t * N_NODES;
    const int* sd = segdst + (long)t * N_NODES;
    const int* ro = rowof + (long)t * N_NODES;
    const int* zl = zlist + (long)t * N_NODES;
    int k = t + 1;  // prefetched lstm step
    const float* hxc = (k & 1) ? hxB : hxA;
    float* hxn = (k & 1) ? hxA : hxB;
    k_A<<<GB + B_LSTM5, 512, 0, stream>>>(
        ss, sl, sedge, hb, WtT + (long)t * 2 * 16384, P2b, nsegp,
        hxc, hxn, cx, Wih, Whh, bih, bhh, meta, WtT + (long)k * 2 * 16384, k);
    k_B<<<GB + B_ZZ, 512, 0, stream>>>(
        ss, sl, sedge, P2b, ro, WtT + ((long)t * 2 + 1) * 16384, hb, sd, nsegp,
        zl, nzp);
  }

  k_segmax<<<B_SEGMAX, 256, 0, stream>>>(hb, gid, keys);
  k_final<<<1, 64, 0, stream>>>(keys, outW, outB, y, out);
}

// Round 12
// 303.670 us; speedup vs baseline: 1.3291x; 1.0683x over previous
//
#include <hip/hip_runtime.h>
#include <hip/hip_bf16.h>
#include <math.h>

#define N_NODES 60000
#define E_EDGES 200000
#define DIM     128
#define NINPK   256
#define TSTEPS  6
#define LLAYERS 2
#define BGRAPH  16
#define NBINS   (TSTEPS * N_NODES)          // 360000
#define NB      ((NBINS + 1023) / 1024)     // 352 scan blocks
#define NWORDS  15000

#define B_INITP  ((NBINS + 255) / 256)          // 1407
#define B_PREP   16
#define B_HIST   ((E_EDGES + 255) / 256)        // 782
#define B_TGEMM  ((NWORDS + 127) / 128)         // 118
#define B_PLACE2 ((E_EDGES + 1023) / 1024)      // 196 (512 thr, 2 edges/thr)
#define B_EMBED  512
#define B_LSTM5  64                             // 4 cols/block @512 thr
#define GB       ((N_NODES + 127) / 128)        // 469 (dyn early-exit on nseg)
#define B_ZZ     64
#define B_SEGMAX ((N_NODES + 127) / 128)        // 469

typedef float f32x4 __attribute__((ext_vector_type(4)));
typedef short s16x8 __attribute__((ext_vector_type(8)));
typedef short s16x4 __attribute__((ext_vector_type(4)));

static __device__ __forceinline__ float sigm(float x) { return 1.f / (1.f + expf(-x)); }

static __device__ __forceinline__ short f2bf(float f) {
  unsigned u = __float_as_uint(f);
  u += 0x7FFFu + ((u >> 16) & 1u);
  return (short)(u >> 16);
}
static __device__ __forceinline__ float bf2f(short s) {
  return __uint_as_float(((unsigned)(unsigned short)s) << 16);
}
static __device__ __forceinline__ unsigned fenc(float f) {
  unsigned u = __float_as_uint(f);
  return (u & 0x80000000u) ? ~u : (u | 0x80000000u);
}
static __device__ __forceinline__ float fdec(unsigned u) {
  u = (u & 0x80000000u) ? (u & 0x7fffffffu) : ~u;
  return __uint_as_float(u);
}

// ============ device bodies ============

// ---- 256-thread GEMM compute+epi (used by table GEMM only) ----
template <bool RELU, bool BIAS, bool GOUT>
static __device__ __forceinline__ void gemm_compute_epi256(
    f32x4 (&acc)[2][8], const short* WtKt, const float* bias, short* C16,
    const int* dstmap, int N, int n0, const short* As, int rsg, int ktg,
    short* Ws, bool last) {
  const int tid = threadIdx.x;
  const int lane = tid & 63;
  const int w = tid >> 6;
  __syncthreads();
  const int4* wg = reinterpret_cast<const int4*>(WtKt);
  int4* wl = reinterpret_cast<int4*>(Ws);
#pragma unroll
  for (int p = 0; p < 4; ++p) wl[p * 256 + tid] = wg[p * 256 + tid];
  __syncthreads();
#pragma unroll
  for (int kk = 0; kk < 2; ++kk) {
    int gb = kk * 4 + (lane >> 4);
    s16x8 a[2];
#pragma unroll
    for (int fr = 0; fr < 2; ++fr) {
      int row = w * 32 + fr * 16 + (lane & 15);
      a[fr] = *(const s16x8*)&As[(row * rsg + ktg + (gb ^ (row & 7))) * 8];
    }
#pragma unroll
    for (int fc = 0; fc < 8; ++fc) {
      int col = fc * 16 + (lane & 15);
      s16x8 b = *(const s16x8*)&Ws[(col * 8 + (gb ^ (col & 7))) * 8];
      acc[0][fc] = __builtin_amdgcn_mfma_f32_16x16x32_bf16(a[0], b, acc[0][fc], 0, 0, 0);
      acc[1][fc] = __builtin_amdgcn_mfma_f32_16x16x32_bf16(a[1], b, acc[1][fc], 0, 0, 0);
    }
  }
  if (!last) return;
  const int cb = lane & 15;
  const int rb = w * 32 + (lane >> 4) * 4;
#pragma unroll
  for (int fr = 0; fr < 2; ++fr) {
#pragma unroll
    for (int reg = 0; reg < 4; ++reg) {
      int n = n0 + rb + fr * 16 + reg;
      if (n >= N) continue;
      long drow = GOUT ? (long)dstmap[n] : (long)n;
      short* cp = C16 + drow * DIM;
#pragma unroll
      for (int fc = 0; fc < 8; ++fc) {
        float x = acc[fr][fc][reg];
        if (BIAS) x += bias[fc * 16 + cb];
        if (RELU) x = fmaxf(x, 0.f);
        cp[fc * 16 + cb] = f2bf(x);
      }
    }
  }
}

// ---- 512-thread fused segscatter+GEMM, latency-overlapped staging ----
// phase 0: each thread owns 4 (row, dim-slice) cells; the 4 dependent load
// chains (segstart/len -> sedge -> ro -> row gather) are issued batched so
// they overlap; tail edges (len>1) walk serially. phase 1: 8 waves MFMA.
template <bool PACKEDIN, bool GOUT>
static __device__ __forceinline__ void fusedgemm512(
    const int* __restrict__ ss, const int* __restrict__ sl,
    const int2* __restrict__ sedge, const short* __restrict__ IN16,
    const int* __restrict__ ro, const short* __restrict__ Wt,
    short* __restrict__ C16, const int* __restrict__ sd,
    const int* __restrict__ nsegp, short* As2, short* Ws, int bid) {
  const int N = nsegp[0];
  const int n0 = bid * 128;
  if (n0 >= N) return;
  const int tid = threadIdx.x;        // 0..511
  const int lane16 = tid & 15;
  const int grp = tid >> 4;           // 0..31
  // --- batched prefetch across the 4 row-iterations ---
  int st[4], ln[4];
#pragma unroll
  for (int it = 0; it < 4; ++it) {
    int seg = n0 + it * 32 + grp;
    bool ok = seg < N;
    st[it] = ok ? ss[seg] : 0;
    ln[it] = ok ? sl[seg] : 0;
  }
  int2 e0[4];
#pragma unroll
  for (int it = 0; it < 4; ++it)
    e0[it] = ln[it] ? sedge[st[it]] : make_int2(0, 0);
  int r0[4];
#pragma unroll
  for (int it = 0; it < 4; ++it)
    r0[it] = ln[it] ? (PACKEDIN ? ro[e0[it].x] : e0[it].x) : -1;
  s16x8 h0[4];
#pragma unroll
  for (int it = 0; it < 4; ++it) {
    s16x8 z = {};
    h0[it] = (r0[it] >= 0) ? *(const s16x8*)&IN16[(long)r0[it] * DIM + lane16 * 8] : z;
  }
  // --- accumulate + write As2 ---
#pragma unroll
  for (int it = 0; it < 4; ++it) {
    int row = it * 32 + grp;
    float a0 = 0, a1 = 0, a2 = 0, a3 = 0, a4 = 0, a5 = 0, a6 = 0, a7 = 0;
    if (ln[it] && r0[it] >= 0) {
      float w = __int_as_float(e0[it].y);
      a0 = w * bf2f(h0[it][0]); a1 = w * bf2f(h0[it][1]);
      a2 = w * bf2f(h0[it][2]); a3 = w * bf2f(h0[it][3]);
      a4 = w * bf2f(h0[it][4]); a5 = w * bf2f(h0[it][5]);
      a6 = w * bf2f(h0[it][6]); a7 = w * bf2f(h0[it][7]);
    }
    for (int e = st[it] + 1; e < st[it] + ln[it]; ++e) {
      int2 v = sedge[e];
      int r2 = PACKEDIN ? ro[v.x] : v.x;
      if (PACKEDIN && r2 < 0) continue;
      float w = __int_as_float(v.y);
      s16x8 hv = *(const s16x8*)&IN16[(long)r2 * DIM + lane16 * 8];
      a0 = fmaf(w, bf2f(hv[0]), a0); a1 = fmaf(w, bf2f(hv[1]), a1);
      a2 = fmaf(w, bf2f(hv[2]), a2); a3 = fmaf(w, bf2f(hv[3]), a3);
      a4 = fmaf(w, bf2f(hv[4]), a4); a5 = fmaf(w, bf2f(hv[5]), a5);
      a6 = fmaf(w, bf2f(hv[6]), a6); a7 = fmaf(w, bf2f(hv[7]), a7);
    }
    s16x8 outv;
    outv[0] = f2bf(a0); outv[1] = f2bf(a1); outv[2] = f2bf(a2); outv[3] = f2bf(a3);
    outv[4] = f2bf(a4); outv[5] = f2bf(a5); outv[6] = f2bf(a6); outv[7] = f2bf(a7);
    int slot = (lane16 & 8) | ((lane16 & 7) ^ (row & 7));
    *(s16x8*)&As2[(row * 16 + slot) * 8] = outv;
  }
  const int lane = tid & 63;
  const int w = tid >> 6;             // 0..7 waves
  f32x4 acc[8] = {};
#pragma unroll
  for (int kt = 0; kt < 2; ++kt) {
    __syncthreads();                  // As2 ready / prior Ws reads done
    const int4* wg = reinterpret_cast<const int4*>(Wt + kt * 128 * 64);
    int4* wl = reinterpret_cast<int4*>(Ws);
#pragma unroll
    for (int p = 0; p < 2; ++p) wl[p * 512 + tid] = wg[p * 512 + tid];
    __syncthreads();
#pragma unroll
    for (int kk = 0; kk < 2; ++kk) {
      int gb = kk * 4 + (lane >> 4);
      int row = w * 16 + (lane & 15);
      s16x8 a = *(const s16x8*)&As2[(row * 16 + kt * 8 + (gb ^ (row & 7))) * 8];
#pragma unroll
      for (int fc = 0; fc < 8; ++fc) {
        int col = fc * 16 + (lane & 15);
        s16x8 b = *(const s16x8*)&Ws[(col * 8 + (gb ^ (col & 7))) * 8];
        acc[fc] = __builtin_amdgcn_mfma_f32_16x16x32_bf16(a, b, acc[fc], 0, 0, 0);
      }
    }
  }
  // epilogue: C/D layout col=lane&15, row=(lane>>4)*4+reg  [m89-verified]
  const int cb = lane & 15;
  const int rb = w * 16 + (lane >> 4) * 4;
#pragma unroll
  for (int reg = 0; reg < 4; ++reg) {
    int n = n0 + rb + reg;
    if (n >= N) continue;
    long drow = GOUT ? (long)sd[n] : (long)n;
    short* cp = C16 + drow * DIM;
#pragma unroll
    for (int fc = 0; fc < 8; ++fc) {
      float x = fmaxf(acc[fc][reg], 0.f);
      cp[fc * 16 + cb] = f2bf(x);
    }
  }
}

// table GEMM (256 thr): table16[w] = wemb[w] @ WtAd + adb
static __device__ __forceinline__ void tablegemm_body(
    const float* __restrict__ Af, const short* __restrict__ Wt,
    const float* __restrict__ bias, short* __restrict__ table16, short* As,
    short* Ws, int bid) {
  const int n0 = bid * 128;
  const int tid = threadIdx.x;
  f32x4 acc[2][8] = {};
#pragma unroll
  for (int kt = 0; kt < 4; ++kt) {
    __syncthreads();
#pragma unroll
    for (int p = 0; p < 4; ++p) {
      int gi = p * 256 + tid;
      int row = gi >> 3, s = gi & 7;
      int n = n0 + row;
      s16x8 v = {};
      if (n < NWORDS) {
        const float* ap = Af + (long)n * NINPK + kt * 64 + (s ^ (row & 7)) * 8;
        float4 v0 = *reinterpret_cast<const float4*>(ap);
        float4 v1 = *reinterpret_cast<const float4*>(ap + 4);
        v[0] = f2bf(v0.x); v[1] = f2bf(v0.y); v[2] = f2bf(v0.z); v[3] = f2bf(v0.w);
        v[4] = f2bf(v1.x); v[5] = f2bf(v1.y); v[6] = f2bf(v1.z); v[7] = f2bf(v1.w);
      }
      *(s16x8*)&As[(row * 8 + s) * 8] = v;
    }
    gemm_compute_epi256<false, true, false>(acc, Wt + kt * 128 * 64, bias, table16,
                                            nullptr, NWORDS, n0, As, 8, 0, Ws,
                                            kt == 3);
  }
}

// zero src-only touched hb rows (512 thr, 16B/lane)
static __device__ __forceinline__ void zzero_body(short* __restrict__ hb,
                                                  const int* __restrict__ zl,
                                                  const int* __restrict__ nzp,
                                                  int bid, int nblocks) {
  int nz = nzp[0];
  int l = threadIdx.x & 15;
  s16x8 z = {};
  for (int s = bid * 32 + (threadIdx.x >> 4); s < nz; s += nblocks * 32) {
    *reinterpret_cast<s16x8*>(&hb[(long)zl[s] * DIM + l * 8]) = z;
  }
}

// fused LSTM step k (512 thr, 4 cols/block): gates, select, hx/cx update,
// writes bf16 weight tiles WtBase + layer*16384
static __device__ __forceinline__ void lstm_body512(
    int bid, const float* __restrict__ hxc, float* __restrict__ hxn,
    float* __restrict__ cx, const float* __restrict__ Wih,
    const float* __restrict__ Whh, const float* __restrict__ bih,
    const float* __restrict__ bhh, const int* __restrict__ meta,
    short* __restrict__ WtBase, int k, float* wi, float* wh) {
  int tid = threadIdx.x;               // 0..511
  int i = bid >> 5;                    // layer (64 blocks: 32/layer)
  int j4 = bid & 31;
  int jl = tid >> 7;                   // 0..3
  int r = tid & 127;
  int j = j4 * 4 + jl;
  float* wiL = wi + jl * 512;
  float* whL = wh + jl * 512;
#pragma unroll
  for (int g4 = 0; g4 < 4; ++g4) {
    wiL[g4 * 128 + r] = Wih[((long)i * 512 + g4 * 128 + j) * DIM + r];
    whL[g4 * 128 + r] = Whh[((long)i * 512 + g4 * 128 + j) * DIM + r];
  }
  __syncthreads();
  const float4* x4 = reinterpret_cast<const float4*>(hxc + ((long)i * DIM + r) * DIM);
  float a0 = 0, a1 = 0, a2 = 0, a3 = 0, b0 = 0, b1 = 0, b2 = 0, b3 = 0;
#pragma unroll 4
  for (int k4 = 0; k4 < 32; ++k4) {
    float4 xv = x4[k4];
    const float* vp = &xv.x;
#pragma unroll
    for (int q = 0; q < 4; ++q) {
      int kk = k4 * 4 + q;
      float xs = vp[q];
      a0 = fmaf(xs, wiL[kk], a0);       a1 = fmaf(xs, wiL[128 + kk], a1);
      a2 = fmaf(xs, wiL[256 + kk], a2); a3 = fmaf(xs, wiL[384 + kk], a3);
      b0 = fmaf(xs, whL[kk], b0);       b1 = fmaf(xs, whL[128 + kk], b1);
      b2 = fmaf(xs, whL[256 + kk], b2); b3 = fmaf(xs, whL[384 + kk], b3);
    }
  }
  int cbi = i * 512 + j;
  float g0i = a0 + bih[cbi] + bhh[cbi];
  float g0f = a1 + bih[cbi + 128] + bhh[cbi + 128];
  float g0g = a2 + bih[cbi + 256] + bhh[cbi + 256];
  float g0o = a3 + bih[cbi + 384] + bhh[cbi + 384];
  float g1i = g0i + b0, g1f = g0f + b1, g1g = g0g + b2, g1o = g0o + b3;
  int idx = i * 16384 + r * 128 + j;
  float c0v = cx[idx];
  float c_zero = sigm(g0i) * tanhf(g0g);
  float h_zero = sigm(g0o) * tanhf(c_zero);
  float c_st = sigm(g1f) * c0v + sigm(g1i) * tanhf(g1g);
  float h_st = sigm(g1o) * tanhf(c_st);
  int first = meta[8 + k];
  int has = meta[k] > 0;
  float hi_v = first ? h_st : h_zero;
  float ci_v = first ? c0v : c_zero;
  float xj = reinterpret_cast<const float*>(x4)[j];
  float hnew = has ? hi_v : xj;
  float cnew = has ? ci_v : c0v;
  hxn[idx] = hnew;
  cx[idx] = cnew;
  short* Wt = WtBase + i * 16384;
  int kb = r >> 6, g = (r >> 3) & 7, jj = r & 7;
  Wt[((kb * DIM + j) * 8 + (g ^ (j & 7))) * 8 + jj] = f2bf(hnew);
}

// ============ kernels ============

// setup0: init state/hist/flags/meta/keys + adaptW bf16 tiles
__global__ void k_setup0(const float* __restrict__ gcn, float* __restrict__ hxA,
                         float* __restrict__ cx, int* __restrict__ meta,
                         unsigned* __restrict__ keys, int* __restrict__ hist,
                         unsigned* __restrict__ flagbits,
                         const float* __restrict__ adW, short* __restrict__ WtAd) {
  int bid = blockIdx.x;
  int tid = threadIdx.x;
  if (bid < B_INITP) {
    int i = bid * 256 + tid;
    if (i < LLAYERS * DIM * DIM) { hxA[i] = gcn[i]; cx[i] = 0.f; }
    if (i < BGRAPH * DIM) keys[i] = 0u;
    if (i < 64) meta[i] = 0;
    if (i < NBINS) hist[i] = 0;
    if (i < (NBINS + 31) / 32) flagbits[i] = 0u;
  } else {
    int idx = (bid - B_INITP) * 256 + tid;  // < 4096
    int g = idx & 7;
    int c = (idx >> 3) & 127;
    int kb = idx >> 10;
    s16x8 s;
#pragma unroll
    for (int j = 0; j < 8; ++j) s[j] = f2bf(adW[(long)(kb * 64 + g * 8 + j) * DIM + c]);
    *(s16x8*)&WtAd[(((long)kb * DIM + c) * 8 + (g ^ (c & 7))) * 8] = s;
  }
}

// hist/flag atomics + table GEMM (fp32 wemb direct), 256 thr
__global__ __launch_bounds__(256) void k_histg(
    const int* __restrict__ et, const int* __restrict__ src,
    const int* __restrict__ dst, int* __restrict__ hist,
    unsigned* __restrict__ flagbits, const float* __restrict__ wemb,
    const short* __restrict__ WtAd, const float* __restrict__ adb,
    short* __restrict__ table16) {
  __shared__ short As[128 * 64];
  __shared__ short Ws[128 * 64];
  int bid = blockIdx.x;
  if (bid < B_HIST) {
    int e = bid * 256 + threadIdx.x;
    if (e < E_EDGES) {
      int t = et[e];
      atomicAdd(&hist[t * N_NODES + dst[e]], 1);
      int fs = t * N_NODES + src[e];
      atomicOr(&flagbits[fs >> 5], 1u << (fs & 31));
    }
  } else {
    tablegemm_body(wemb, WtAd, adb, table16, As, Ws, bid - B_HIST);
  }
}

// fused 2-level exclusive scan: hist values, nonempty indicator, z indicator
__global__ void k_scan1b(const int* __restrict__ hist,
                         const unsigned* __restrict__ flagbits,
                         int* __restrict__ scanA, int* __restrict__ scanB,
                         int* __restrict__ scanC, int* __restrict__ bsumA,
                         int* __restrict__ bsumB, int* __restrict__ bsumC) {
  __shared__ int shA[256], shB[256], shC[256];
  int b0 = blockIdx.x * 1024;
  int tid = threadIdx.x;
  int v[4], w[4], z[4];
  int sA = 0, sB = 0, sC = 0;
#pragma unroll
  for (int q = 0; q < 4; ++q) {
    int i = b0 + tid * 4 + q;
    int c = (i < NBINS) ? hist[i] : 0;
    int fl = (i < NBINS) ? (int)((flagbits[i >> 5] >> (i & 31)) & 1u) : 0;
    v[q] = c; w[q] = (c > 0) ? 1 : 0; z[q] = (fl && c == 0) ? 1 : 0;
    sA += c; sB += w[q]; sC += z[q];
  }
  shA[tid] = sA; shB[tid] = sB; shC[tid] = sC;
  __syncthreads();
  for (int off = 1; off < 256; off <<= 1) {
    int xA = (tid >= off) ? shA[tid - off] : 0;
    int xB = (tid >= off) ? shB[tid - off] : 0;
    int xC = (tid >= off) ? shC[tid - off] : 0;
    __syncthreads();
    shA[tid] += xA; shB[tid] += xB; shC[tid] += xC;
    __syncthreads();
  }
  int exA = shA[tid] - sA, exB = shB[tid] - sB, exC = shC[tid] - sC;
#pragma unroll
  for (int q = 0; q < 4; ++q) {
    int i = b0 + tid * 4 + q;
    if (i < NBINS) { scanA[i] = exA; scanB[i] = exB; scanC[i] = exC; }
    exA += v[q]; exB += w[q]; exC += z[q];
  }
  if (tid == 255) {
    bsumA[blockIdx.x] = shA[255];
    bsumB[blockIdx.x] = shB[255];
    bsumC[blockIdx.x] = shC[255];
  }
}

// parallel block-sum scan (3 channels) + all meta fields
__global__ __launch_bounds__(256) void k_scan2p(
    int* __restrict__ bsumA, int* __restrict__ bsumB, int* __restrict__ bsumC,
    const int* __restrict__ scanA, const int* __restrict__ scanB,
    const int* __restrict__ scanC, int* __restrict__ meta) {
  __shared__ int pA[256], pB[256], pC[256];
  __shared__ int eA[512], eB[512], eC[512];
  int tid = threadIdx.x;
  int i0 = tid * 2, i1 = tid * 2 + 1;
  int a0 = (i0 < NB) ? bsumA[i0] : 0, a1 = (i1 < NB) ? bsumA[i1] : 0;
  int b0 = (i0 < NB) ? bsumB[i0] : 0, b1 = (i1 < NB) ? bsumB[i1] : 0;
  int c0 = (i0 < NB) ? bsumC[i0] : 0, c1 = (i1 < NB) ? bsumC[i1] : 0;
  int tA = a0 + a1, tB = b0 + b1, tC = c0 + c1;
  pA[tid] = tA; pB[tid] = tB; pC[tid] = tC;
  __syncthreads();
  for (int off = 1; off < 256; off <<= 1) {
    int xA = (tid >= off) ? pA[tid - off] : 0;
    int xB = (tid >= off) ? pB[tid - off] : 0;
    int xC = (tid >= off) ? pC[tid - off] : 0;
    __syncthreads();
    pA[tid] += xA; pB[tid] += xB; pC[tid] += xC;
    __syncthreads();
  }
  int baseA = pA[tid] - tA, baseB = pB[tid] - tB, baseC = pC[tid] - tC;
  eA[i0] = baseA; eA[i1] = baseA + a0;
  eB[i0] = baseB; eB[i1] = baseB + b0;
  eC[i0] = baseC; eC[i1] = baseC + c0;
  if (i0 < NB) { bsumA[i0] = baseA; bsumB[i0] = baseB; bsumC[i0] = baseC; }
  if (i1 < NB) { bsumA[i1] = baseA + a0; bsumB[i1] = baseB + b0; bsumC[i1] = baseC + c0; }
  __syncthreads();
  if (tid == 0) {
    int loA[TSTEPS + 1], loB[TSTEPS + 1], loC[TSTEPS + 1];
    for (int t = 0; t < TSTEPS; ++t) {
      int ib = t * N_NODES, blk = ib >> 10;
      loA[t] = scanA[ib] + eA[blk];
      loB[t] = scanB[ib] + eB[blk];
      loC[t] = scanC[ib] + eC[blk];
    }
    loA[TSTEPS] = pA[255]; loB[TSTEPS] = pB[255]; loC[TSTEPS] = pC[255];
    int f = 0;
    for (int t = 0; t < TSTEPS; ++t) {
      int cnt = loA[t + 1] - loA[t];
      meta[t] = cnt;
      meta[8 + t] = f; f |= (cnt > 0);
      meta[32 + t] = loB[t + 1] - loB[t];   // segcnt
      meta[48 + t] = loB[t];                // seg rank base
      meta[40 + t] = loC[t + 1] - loC[t];   // zcnt
      meta[56 + t] = loC[t];                // z rank base
    }
  }
}

// finalize scan; build segments + rowof (+ -1 fill) + zlist via scan ranks
__global__ void k_scan3seg(int* __restrict__ scanA, const int* __restrict__ bsumA,
                           const int* __restrict__ scanB, const int* __restrict__ bsumB,
                           const int* __restrict__ scanC, const int* __restrict__ bsumC,
                           const int* __restrict__ hist,
                           const unsigned* __restrict__ flagbits,
                           const int* __restrict__ meta, int* __restrict__ segdst,
                           int* __restrict__ segstart, int* __restrict__ seglen,
                           int* __restrict__ rowof, int* __restrict__ zlist) {
  int i = blockIdx.x * blockDim.x + threadIdx.x;
  if (i >= NBINS) return;
  int vA = scanA[i] + bsumA[i >> 10];
  scanA[i] = vA;
  int c = hist[i];
  int t = i / N_NODES;
  int tb = t * N_NODES;
  if (c > 0) {
    int sidx = scanB[i] + bsumB[i >> 10] - meta[48 + t];
    long sb = (long)tb + sidx;
    segdst[sb] = i - tb;
    segstart[sb] = vA;
    seglen[sb] = c;
    rowof[i] = sidx;
  } else {
    rowof[i] = -1;
    if ((flagbits[i >> 5] >> (i & 31)) & 1u) {
      int zr = scanC[i] + bsumC[i >> 10] - meta[56 + t];
      zlist[(long)tb + zr] = i - tb;
    }
  }
}

// setup1 (512 thr): place edges (2/thread, interleaved chains) + embed + lstm(0)
__global__ __launch_bounds__(512) void k_setup1(
    const int* __restrict__ et, const int* __restrict__ src,
    const int* __restrict__ dst, const float* __restrict__ ew,
    int* __restrict__ scanA, int2* __restrict__ sedge,
    const short* __restrict__ table16, const int* __restrict__ wid,
    short* __restrict__ hb, const float* __restrict__ hxA, float* __restrict__ hxB,
    float* __restrict__ cx, const float* __restrict__ Wih,
    const float* __restrict__ Whh, const float* __restrict__ bih,
    const float* __restrict__ bhh, const int* __restrict__ meta,
    short* __restrict__ WtT) {
  __shared__ float lb[4096];
  int bid = blockIdx.x;
  int tid = threadIdx.x;
  if (bid < B_PLACE2) {
    int e0 = bid * 1024 + tid;
    int e1 = e0 + 512;
    bool ok0 = e0 < E_EDGES, ok1 = e1 < E_EDGES;
    int t0 = ok0 ? et[e0] : 0, t1 = ok1 ? et[e1] : 0;
    int d0 = ok0 ? dst[e0] : 0, d1 = ok1 ? dst[e1] : 0;
    int s0 = ok0 ? src[e0] : 0, s1 = ok1 ? src[e1] : 0;
    float w0 = ok0 ? ew[e0] : 0.f, w1 = ok1 ? ew[e1] : 0.f;
    int p0 = ok0 ? atomicAdd(&scanA[t0 * N_NODES + d0], 1) : 0;
    int p1 = ok1 ? atomicAdd(&scanA[t1 * N_NODES + d1], 1) : 0;
    if (ok0) sedge[p0] = make_int2(s0, __float_as_int(w0));
    if (ok1) sedge[p1] = make_int2(s1, __float_as_int(w1));
  } else if (bid < B_PLACE2 + B_EMBED) {
    int l = tid & 15;
    for (int n = (bid - B_PLACE2) * 32 + (tid >> 4); n < N_NODES; n += B_EMBED * 32) {
      *reinterpret_cast<s16x8*>(&hb[(long)n * DIM + l * 8]) =
          *reinterpret_cast<const s16x8*>(&table16[(long)wid[n] * DIM + l * 8]);
    }
  } else {
    lstm_body512(bid - B_PLACE2 - B_EMBED, hxA, hxB, cx, Wih, Whh, bih, bhh, meta,
                 WtT, 0, lb, lb + 2048);
  }
}

// loop launch A (512 thr): fused scat0+gemm0 ∥ lstm(t+1)
__global__ __launch_bounds__(512) void k_A(
    const int* __restrict__ ss, const int* __restrict__ sl,
    const int2* __restrict__ sedge, const short* __restrict__ hb,
    const short* __restrict__ Wt0, short* __restrict__ P2b,
    const int* __restrict__ nsegp, const float* __restrict__ hxc,
    float* __restrict__ hxn, float* __restrict__ cx,
    const float* __restrict__ Wih, const float* __restrict__ Whh,
    const float* __restrict__ bih, const float* __restrict__ bhh,
    const int* __restrict__ meta, short* __restrict__ WtNext, int k) {
  __shared__ short As2[128 * 128];
  __shared__ short Ws[128 * 64];
  int bid = blockIdx.x;
  if (bid < GB) {
    fusedgemm512<false, false>(ss, sl, sedge, hb, nullptr, Wt0, P2b, nullptr,
                               nsegp, As2, Ws, bid);
  } else if (k < TSTEPS) {
    float* lb = (float*)As2;
    lstm_body512(bid - GB, hxc, hxn, cx, Wih, Whh, bih, bhh, meta, WtNext, k,
                 lb, lb + 2048);
  }
}

// loop launch B (512 thr): fused scat1+gemm1 ∥ zzero
__global__ __launch_bounds__(512) void k_B(
    const int* __restrict__ ss, const int* __restrict__ sl,
    const int2* __restrict__ sedge, const short* __restrict__ P2b,
    const int* __restrict__ ro, const short* __restrict__ Wt1,
    short* __restrict__ hb, const int* __restrict__ sd,
    const int* __restrict__ nsegp, const int* __restrict__ zl,
    const int* __restrict__ nzp) {
  __shared__ short As2[128 * 128];
  __shared__ short Ws[128 * 64];
  int bid = blockIdx.x;
  if (bid < GB) {
    fusedgemm512<true, true>(ss, sl, sedge, P2b, ro, Wt1, hb, sd, nsegp,
                             As2, Ws, bid);
  } else {
    zzero_body(hb, zl, nzp, bid - GB, B_ZZ);
  }
}

// segment max: vectorized 16B loads, LDS tree reduce, atomicMax only.
// NO device fences — cross-kernel visibility via dispatch boundary.
__global__ __launch_bounds__(256) void k_segmax(
    const short* __restrict__ hb, const int* __restrict__ gid,
    unsigned* __restrict__ keys) {
  __shared__ float red[256 * 8];
  int tid = threadIdx.x;
  int c = tid & 15;   // dim group: dims c*8 .. c*8+7
  int r = tid >> 4;   // row lane
  int n0 = blockIdx.x * 128;
  int nend = min(n0 + 128, N_NODES);
  float m[8];
#pragma unroll
  for (int j = 0; j < 8; ++j) m[j] = -INFINITY;
  if (gid[n0] == gid[nend - 1]) {
    int g = gid[n0];
#pragma unroll
    for (int it = 0; it < 8; ++it) {
      int n = n0 + it * 16 + r;
      if (n < N_NODES) {
        s16x8 v = *(const s16x8*)&hb[(long)n * DIM + c * 8];
#pragma unroll
        for (int j = 0; j < 8; ++j) m[j] = fmaxf(m[j], bf2f(v[j]));
      }
    }
#pragma unroll
    for (int j = 0; j < 8; ++j) red[tid * 8 + j] = m[j];
    __syncthreads();
    for (int off = 8; off >= 1; off >>= 1) {
      if (r < off) {
#pragma unroll
        for (int j = 0; j < 8; ++j)
          red[tid * 8 + j] = fmaxf(red[tid * 8 + j], red[(tid + off * 16) * 8 + j]);
      }
      __syncthreads();
    }
    if (r == 0) {
#pragma unroll
      for (int j = 0; j < 8; ++j)
        atomicMax(&keys[(long)g * DIM + c * 8 + j], fenc(red[tid * 8 + j]));
    }
  } else {
    int curg = -1;
#pragma unroll
    for (int it = 0; it < 8; ++it) {
      int n = n0 + it * 16 + r;
      if (n >= N_NODES) break;
      int g = gid[n];
      if (g != curg) {
        if (curg >= 0) {
#pragma unroll
          for (int j = 0; j < 8; ++j)
            atomicMax(&keys[(long)curg * DIM + c * 8 + j], fenc(m[j]));
        }
        curg = g;
#pragma unroll
        for (int j = 0; j < 8; ++j) m[j] = -INFINITY;
      }
      s16x8 v = *(const s16x8*)&hb[(long)n * DIM + c * 8];
#pragma unroll
      for (int j = 0; j < 8; ++j) m[j] = fmaxf(m[j], bf2f(v[j]));
    }
    if (curg >= 0) {
#pragma unroll
      for (int j = 0; j < 8; ++j)
        atomicMax(&keys[(long)curg * DIM + c * 8 + j], fenc(m[j]));
    }
  }
}

// final: logits, probs, BCE loss (separate dispatch: keys visible at boundary)
__global__ void k_final(const unsigned* __restrict__ keys, const float* __restrict__ outW,
                        const float* __restrict__ outB, const float* __restrict__ y,
                        float* __restrict__ out) {
  __shared__ float lt[BGRAPH];
  int tid = threadIdx.x;
  int b = tid >> 2, l4 = tid & 3;
  float s = 0.f;
  for (int d = l4; d < DIM; d += 4) {
    float v = fdec(keys[(long)b * DIM + d]);
    if (!isfinite(v)) v = 0.f;
    s += v * outW[d];
  }
  s += __shfl_down(s, 1);
  s += __shfl_down(s, 2);
  if (l4 == 0) {
    float l = s + outB[0];
    out[1 + b] = 1.f / (1.f + expf(-l));
    lt[b] = fmaxf(l, 0.f) - l * y[b] + log1pf(expf(-fabsf(l)));
  }
  __syncthreads();
  if (tid == 0) {
    float acc = 0.f;
    for (int i = 0; i < BGRAPH; ++i) acc += lt[i];
    out[0] = acc / (float)BGRAPH;
  }
}

extern "C" void kernel_launch(void* const* d_in, const int* in_sizes, int n_in,
                              void* d_out, int out_size, void* d_ws, size_t ws_size,
                              hipStream_t stream) {
  const int* word_ids = (const int*)d_in[0];
  const int* src = (const int*)d_in[1];
  const int* dst = (const int*)d_in[2];
  const int* et = (const int*)d_in[3];
  const float* ew = (const float*)d_in[4];
  const int* gid = (const int*)d_in[5];
  const float* y = (const float*)d_in[6];
  const float* wemb = (const float*)d_in[7];
  const float* adW = (const float*)d_in[8];
  const float* adb = (const float*)d_in[9];
  const float* gcn = (const float*)d_in[10];
  const float* Wih = (const float*)d_in[11];
  const float* Whh = (const float*)d_in[12];
  const float* bih = (const float*)d_in[13];
  const float* bhh = (const float*)d_in[14];
  const float* outW = (const float*)d_in[15];
  const float* outB = (const float*)d_in[16];
  float* out = (float*)d_out;

  char* ws = (char*)d_ws;
  const long ND = (long)N_NODES * DIM;
  short* hb = (short*)ws;       ws += ND * 2;
  short* P2b = (short*)ws;      ws += ND * 2;
  float* hxA = (float*)ws;      ws += LLAYERS * DIM * DIM * 4;
  float* hxB = (float*)ws;      ws += LLAYERS * DIM * DIM * 4;
  float* cx = (float*)ws;       ws += LLAYERS * DIM * DIM * 4;
  int* meta = (int*)ws;         ws += 64 * 4;
  unsigned* keys = (unsigned*)ws; ws += BGRAPH * DIM * 4;
  int* hist = (int*)ws;         ws += (long)NBINS * 4;
  int* scanA = (int*)ws;        ws += (long)NBINS * 4;
  int* scanB = (int*)ws;        ws += (long)NBINS * 4;
  int* scanC = (int*)ws;        ws += (long)NBINS * 4;
  int* bsumA = (int*)ws;        ws += ((NB + 63) & ~63) * 4;
  int* bsumB = (int*)ws;        ws += ((NB + 63) & ~63) * 4;
  int* bsumC = (int*)ws;        ws += ((NB + 63) & ~63) * 4;
  int* rowof = (int*)ws;        ws += (long)NBINS * 4;
  int* segdst = (int*)ws;       ws += (long)NBINS * 4;
  int* segstart = (int*)ws;     ws += (long)NBINS * 4;
  int* seglen = (int*)ws;       ws += (long)NBINS * 4;
  int* zlist = (int*)ws;        ws += (long)NBINS * 4;
  int2* sedge = (int2*)ws;      ws += (long)E_EDGES * 8;
  unsigned* flagbits = (unsigned*)ws; ws += ((NBINS + 31) / 32 + 64) * 4;
  short* table16 = (short*)ws;  ws += (long)NWORDS * DIM * 2;
  short* WtAd = (short*)ws;     ws += 4L * DIM * 64 * 2;
  short* WtT = (short*)ws;      ws += 7L * 2 * 16384 * 2;  // [t][layer] bf16 tiles

  // ---- setup (6 launches) ----
  k_setup0<<<B_INITP + B_PREP, 256, 0, stream>>>(gcn, hxA, cx, meta, keys, hist,
                                                 flagbits, adW, WtAd);
  k_histg<<<B_HIST + B_TGEMM, 256, 0, stream>>>(et, src, dst, hist, flagbits,
                                                wemb, WtAd, adb, table16);
  k_scan1b<<<NB, 256, 0, stream>>>(hist, flagbits, scanA, scanB, scanC,
                                   bsumA, bsumB, bsumC);
  k_scan2p<<<1, 256, 0, stream>>>(bsumA, bsumB, bsumC, scanA, scanB, scanC, meta);
  k_scan3seg<<<B_INITP, 256, 0, stream>>>(scanA, bsumA, scanB, bsumB, scanC, bsumC,
                                          hist, flagbits, meta, segdst, segstart,
                                          seglen, rowof, zlist);
  k_setup1<<<B_PLACE2 + B_EMBED + B_LSTM5, 512, 0, stream>>>(
      et, src, dst, ew, scanA, sedge, table16, word_ids, hb, hxA, hxB, cx,
      Wih, Whh, bih, bhh, meta, WtT);

  // ---- t-loop (2 launches per step) ----
  for (int t = 0; t < TSTEPS; ++t) {
    const int* nsegp = &meta[32 + t];
    const int* nzp = &meta[40 + t];
    const int* ss = segstart + (long)t * N_NODES;
    const int* sl = seglen + (long)t * N_NODES;
    const int* sd = segdst + (long)t * N_NODES;
    const int* ro = rowof + (long)t * N_NODES;
    const int* zl = zlist + (long)t * N_NODES;
    int k = t + 1;  // prefetched lstm step
    const float* hxc = (k & 1) ? hxB : hxA;
    float* hxn = (k & 1) ? hxA : hxB;
    k_A<<<GB + B_LSTM5, 512, 0, stream>>>(
        ss, sl, sedge, hb, WtT + (long)t * 2 * 16384, P2b, nsegp,
        hxc, hxn, cx, Wih, Whh, bih, bhh, meta, WtT + (long)k * 2 * 16384, k);
    k_B<<<GB + B_ZZ, 512, 0, stream>>>(
        ss, sl, sedge, P2b, ro, WtT + ((long)t * 2 + 1) * 16384, hb, sd, nsegp,
        zl, nzp);
  }

  k_segmax<<<B_SEGMAX, 256, 0, stream>>>(hb, gid, keys);
  k_final<<<1, 64, 0, stream>>>(keys, outW, outB, y, out);
}